// Round 1
// baseline (707.147 us; speedup 1.0000x reference)
//
#include <hip/hip_runtime.h>
#include <cstddef>

// Problem constants
#define BB   128
#define NN   256
#define DIMD 256
#define MSG  64
#define CDIM 32
#define TOPK 8
#define H1D  128
#define H2D  256
#define BN   (BB*NN)   // 32768 rows

// ---------------------------------------------------------------------------
// Kernel A: send pipeline  obs(256) -> relu h(128) -> full_msg(64) -> comp(32)
//           -> msgs(64).  32 rows/block, 256 threads.
// ---------------------------------------------------------------------------
__global__ __launch_bounds__(256) void send_k(
    const float* __restrict__ obs,
    const float* __restrict__ W1, const float* __restrict__ b1,
    const float* __restrict__ W2, const float* __restrict__ b2,
    const float* __restrict__ Wc, const float* __restrict__ bc,
    const float* __restrict__ Wd, const float* __restrict__ bd,
    float* __restrict__ msgs)
{
    __shared__ __align__(16) float s_obs[32][256];
    __shared__ __align__(16) float s_h [32][128];
    __shared__ __align__(16) float s_fm[32][64];
    __shared__ __align__(16) float s_cp[32][32];
    const int t = threadIdx.x;
    const int base = blockIdx.x * 32;

    // stage obs tile (8192 floats = 2048 float4), fully coalesced
    {
        const float4* src = (const float4*)(obs + (size_t)base * DIMD);
        float4* dst = (float4*)(&s_obs[0][0]);
        #pragma unroll
        for (int q = 0; q < 8; ++q) dst[t + 256*q] = src[t + 256*q];
    }
    __syncthreads();

    // L1: 256 -> 128.  cols c0+32k (k<4), rows rg*4+j (j<4)
    {
        const int c0 = t & 31;
        const int rg = t >> 5;
        float acc[4][4];
        #pragma unroll
        for (int k = 0; k < 4; ++k) {
            const float bv = b1[c0 + 32*k];
            #pragma unroll
            for (int j = 0; j < 4; ++j) acc[k][j] = bv;
        }
        for (int d = 0; d < 256; d += 4) {
            float w[4][4];
            #pragma unroll
            for (int dd = 0; dd < 4; ++dd)
                #pragma unroll
                for (int k = 0; k < 4; ++k)
                    w[dd][k] = W1[(d+dd)*H1D + c0 + 32*k];
            #pragma unroll
            for (int j = 0; j < 4; ++j) {
                const float4 o = *(const float4*)&s_obs[rg*4+j][d];
                #pragma unroll
                for (int k = 0; k < 4; ++k)
                    acc[k][j] += o.x*w[0][k] + o.y*w[1][k] + o.z*w[2][k] + o.w*w[3][k];
            }
        }
        #pragma unroll
        for (int k = 0; k < 4; ++k)
            #pragma unroll
            for (int j = 0; j < 4; ++j)
                s_h[rg*4+j][c0 + 32*k] = fmaxf(acc[k][j], 0.0f);
    }
    __syncthreads();

    // L2: 128 -> 64.  cols c0+16k (k<4), rows r0+j (j<2)
    {
        const int c0 = t & 15;
        const int r0 = (t >> 4) * 2;
        float acc[4][2];
        #pragma unroll
        for (int k = 0; k < 4; ++k) {
            const float bv = b2[c0 + 16*k];
            acc[k][0] = bv; acc[k][1] = bv;
        }
        for (int d = 0; d < 128; d += 4) {
            float w[4][4];
            #pragma unroll
            for (int dd = 0; dd < 4; ++dd)
                #pragma unroll
                for (int k = 0; k < 4; ++k)
                    w[dd][k] = W2[(d+dd)*MSG + c0 + 16*k];
            #pragma unroll
            for (int j = 0; j < 2; ++j) {
                const float4 h = *(const float4*)&s_h[r0+j][d];
                #pragma unroll
                for (int k = 0; k < 4; ++k)
                    acc[k][j] += h.x*w[0][k] + h.y*w[1][k] + h.z*w[2][k] + h.w*w[3][k];
            }
        }
        #pragma unroll
        for (int k = 0; k < 4; ++k)
            #pragma unroll
            for (int j = 0; j < 2; ++j)
                s_fm[r0+j][c0 + 16*k] = acc[k][j];
    }
    __syncthreads();

    // L3: 64 -> 32.  cols c0, c0+16 ; rows r0+j (j<2)
    {
        const int c0 = t & 15;
        const int r0 = (t >> 4) * 2;
        float acc[2][2];
        #pragma unroll
        for (int k = 0; k < 2; ++k) {
            const float bv = bc[c0 + 16*k];
            acc[k][0] = bv; acc[k][1] = bv;
        }
        for (int d = 0; d < 64; d += 4) {
            float w[4][2];
            #pragma unroll
            for (int dd = 0; dd < 4; ++dd)
                #pragma unroll
                for (int k = 0; k < 2; ++k)
                    w[dd][k] = Wc[(d+dd)*CDIM + c0 + 16*k];
            #pragma unroll
            for (int j = 0; j < 2; ++j) {
                const float4 h = *(const float4*)&s_fm[r0+j][d];
                #pragma unroll
                for (int k = 0; k < 2; ++k)
                    acc[k][j] += h.x*w[0][k] + h.y*w[1][k] + h.z*w[2][k] + h.w*w[3][k];
            }
        }
        #pragma unroll
        for (int k = 0; k < 2; ++k)
            #pragma unroll
            for (int j = 0; j < 2; ++j)
                s_cp[r0+j][c0 + 16*k] = acc[k][j];
    }
    __syncthreads();

    // L4: 32 -> 64 (decompress), write msgs.  cols c0+16k (k<4), rows r0+j
    {
        const int c0 = t & 15;
        const int r0 = (t >> 4) * 2;
        float acc[4][2];
        #pragma unroll
        for (int k = 0; k < 4; ++k) {
            const float bv = bd[c0 + 16*k];
            acc[k][0] = bv; acc[k][1] = bv;
        }
        for (int d = 0; d < 32; d += 4) {
            float w[4][4];
            #pragma unroll
            for (int dd = 0; dd < 4; ++dd)
                #pragma unroll
                for (int k = 0; k < 4; ++k)
                    w[dd][k] = Wd[(d+dd)*MSG + c0 + 16*k];
            #pragma unroll
            for (int j = 0; j < 2; ++j) {
                const float4 h = *(const float4*)&s_cp[r0+j][d];
                #pragma unroll
                for (int k = 0; k < 4; ++k)
                    acc[k][j] += h.x*w[0][k] + h.y*w[1][k] + h.z*w[2][k] + h.w*w[3][k];
            }
        }
        #pragma unroll
        for (int j = 0; j < 2; ++j)
            #pragma unroll
            for (int k = 0; k < 4; ++k)
                msgs[(size_t)(base + r0 + j)*MSG + c0 + 16*k] = acc[k][j];
    }
}

// ---------------------------------------------------------------------------
// Kernel B: bilinear relevance + top-k softmax gating + message aggregation.
//   Per block: one batch b, 32 receiver rows.  tmp = obs_i @ Wbil (LDS),
//   S = tmp @ obs_b^T + bbil (LDS), then per-row wave top-8 / softmax / agg.
// ---------------------------------------------------------------------------
__global__ __launch_bounds__(256) void rel_k(
    const float* __restrict__ obs,
    const float* __restrict__ Wbil, const float* __restrict__ bbil,
    const float* __restrict__ msgs, float* __restrict__ agg)
{
    __shared__ __align__(16) float sX[32][256];   // obs_i tile, later scores
    __shared__ __align__(16) float sT[32][256];   // tmp tile
    const int t  = threadIdx.x;
    const int b  = blockIdx.x >> 3;
    const int ib = (blockIdx.x & 7) * 32;
    const float* obs_b = obs + (size_t)b * NN * DIMD;

    // stage obs_i tile
    {
        const float4* src = (const float4*)(obs_b + (size_t)ib * DIMD);
        float4* dst = (float4*)(&sX[0][0]);
        #pragma unroll
        for (int q = 0; q < 8; ++q) dst[t + 256*q] = src[t + 256*q];
    }
    __syncthreads();

    const int c0 = t & 31;   // col/j group base
    const int rg = t >> 5;   // row group: rows rg*4+j

    // phase 2: tmp[r][c] = sum_d obs_i[r][d] * Wbil[d][c]
    {
        float acc[8][4];
        #pragma unroll
        for (int k = 0; k < 8; ++k)
            #pragma unroll
            for (int j = 0; j < 4; ++j) acc[k][j] = 0.0f;
        for (int d = 0; d < 256; d += 4) {
            float w[4][8];
            #pragma unroll
            for (int dd = 0; dd < 4; ++dd)
                #pragma unroll
                for (int k = 0; k < 8; ++k)
                    w[dd][k] = Wbil[(d+dd)*DIMD + c0 + 32*k];
            #pragma unroll
            for (int j = 0; j < 4; ++j) {
                const float4 o = *(const float4*)&sX[rg*4+j][d];
                #pragma unroll
                for (int k = 0; k < 8; ++k)
                    acc[k][j] += o.x*w[0][k] + o.y*w[1][k] + o.z*w[2][k] + o.w*w[3][k];
            }
        }
        #pragma unroll
        for (int k = 0; k < 8; ++k)
            #pragma unroll
            for (int j = 0; j < 4; ++j)
                sT[rg*4+j][c0 + 32*k] = acc[k][j];
    }
    __syncthreads();

    // phase 3: S[r][jcol] = sum_d tmp[r][d] * obs_b[jcol][d] + bbil
    {
        const float bb = bbil[0];
        float acc[8][4];
        #pragma unroll
        for (int k = 0; k < 8; ++k)
            #pragma unroll
            for (int j = 0; j < 4; ++j) acc[k][j] = 0.0f;
        for (int d = 0; d < 256; d += 4) {
            float4 ov[8];
            #pragma unroll
            for (int k = 0; k < 8; ++k)
                ov[k] = *(const float4*)&obs_b[(size_t)(c0 + 32*k)*DIMD + d];
            #pragma unroll
            for (int j = 0; j < 4; ++j) {
                const float4 tv = *(const float4*)&sT[rg*4+j][d];
                #pragma unroll
                for (int k = 0; k < 8; ++k)
                    acc[k][j] += tv.x*ov[k].x + tv.y*ov[k].y + tv.z*ov[k].z + tv.w*ov[k].w;
            }
        }
        #pragma unroll
        for (int k = 0; k < 8; ++k)
            #pragma unroll
            for (int j = 0; j < 4; ++j)
                sX[rg*4+j][c0 + 32*k] = acc[k][j] + bb;   // scores overwrite obs_i
    }
    __syncthreads();

    // phase 4: per-row top-8 (lowest-index tie-break), softmax, gather msgs
    {
        const int wave = t >> 6;
        const int lane = t & 63;
        for (int rr = 0; rr < 8; ++rr) {
            const int r = wave * 8 + rr;
            float v[4];
            #pragma unroll
            for (int q = 0; q < 4; ++q) v[q] = sX[r][lane + 64*q];

            float topv[TOPK]; int topi[TOPK];
            #pragma unroll
            for (int k = 0; k < TOPK; ++k) {
                float bv = -3.4028235e38f; int bi = 1 << 30;
                #pragma unroll
                for (int q = 0; q < 4; ++q) {
                    const int id = lane + 64*q;
                    bool excl = false;
                    #pragma unroll
                    for (int kk = 0; kk < TOPK; ++kk)
                        if (kk < k && topi[kk] == id) excl = true;
                    if (!excl && v[q] > bv) { bv = v[q]; bi = id; }
                }
                #pragma unroll
                for (int off = 32; off > 0; off >>= 1) {
                    const float ovv = __shfl_xor(bv, off);
                    const int   oii = __shfl_xor(bi, off);
                    if (ovv > bv || (ovv == bv && oii < bi)) { bv = ovv; bi = oii; }
                }
                topv[k] = bv; topi[k] = bi;
            }

            float e[TOPK]; float ssum = 0.0f;
            #pragma unroll
            for (int k = 0; k < TOPK; ++k) { e[k] = __expf(topv[k] - topv[0]); ssum += e[k]; }
            const float inv = 1.0f / ssum;

            float a = 0.0f;
            #pragma unroll
            for (int k = 0; k < TOPK; ++k)
                a = fmaf(e[k] * inv, msgs[(size_t)(b*NN + topi[k])*MSG + lane], a);
            agg[(size_t)(b*NN + ib + r)*MSG + lane] = a;
        }
    }
}

// ---------------------------------------------------------------------------
// Kernel C: receiver MLP  [obs(256), agg(64)](320) -> relu(256) -> out(256)
//           32 rows/block, 256 threads, 8col x 4row register tile.
// ---------------------------------------------------------------------------
__global__ __launch_bounds__(256) void recv_k(
    const float* __restrict__ obs, const float* __restrict__ agg,
    const float* __restrict__ Wr1, const float* __restrict__ br1,
    const float* __restrict__ Wr2, const float* __restrict__ br2,
    float* __restrict__ out)
{
    __shared__ __align__(16) float sC[32][320];
    __shared__ __align__(16) float sR[32][256];
    const int t = threadIdx.x;
    const int base = blockIdx.x * 32;

    // stage combined = [obs | agg]
    {
        const float4* so = (const float4*)(obs + (size_t)base * DIMD);
        #pragma unroll
        for (int q = 0; q < 8; ++q) {
            const int idx = t + 256*q;          // float4 index, 2048 total
            const int r = idx >> 6, c4 = idx & 63;
            *(float4*)&sC[r][c4*4] = so[idx];
        }
        const float4* sa = (const float4*)(agg + (size_t)base * MSG);
        #pragma unroll
        for (int q = 0; q < 2; ++q) {
            const int idx = t + 256*q;          // 512 total
            const int r = idx >> 4, c4 = idx & 15;
            *(float4*)&sC[r][256 + c4*4] = sa[idx];
        }
    }
    __syncthreads();

    const int c0 = t & 31;
    const int rg = t >> 5;

    // L1: 320 -> 256, relu
    {
        float acc[8][4];
        #pragma unroll
        for (int k = 0; k < 8; ++k) {
            const float bv = br1[c0 + 32*k];
            #pragma unroll
            for (int j = 0; j < 4; ++j) acc[k][j] = bv;
        }
        for (int d = 0; d < 320; d += 4) {
            float w[4][8];
            #pragma unroll
            for (int dd = 0; dd < 4; ++dd)
                #pragma unroll
                for (int k = 0; k < 8; ++k)
                    w[dd][k] = Wr1[(d+dd)*H2D + c0 + 32*k];
            #pragma unroll
            for (int j = 0; j < 4; ++j) {
                const float4 cc = *(const float4*)&sC[rg*4+j][d];
                #pragma unroll
                for (int k = 0; k < 8; ++k)
                    acc[k][j] += cc.x*w[0][k] + cc.y*w[1][k] + cc.z*w[2][k] + cc.w*w[3][k];
            }
        }
        #pragma unroll
        for (int k = 0; k < 8; ++k)
            #pragma unroll
            for (int j = 0; j < 4; ++j)
                sR[rg*4+j][c0 + 32*k] = fmaxf(acc[k][j], 0.0f);
    }
    __syncthreads();

    // L2: 256 -> 256, write out
    {
        float acc[8][4];
        #pragma unroll
        for (int k = 0; k < 8; ++k) {
            const float bv = br2[c0 + 32*k];
            #pragma unroll
            for (int j = 0; j < 4; ++j) acc[k][j] = bv;
        }
        for (int d = 0; d < 256; d += 4) {
            float w[4][8];
            #pragma unroll
            for (int dd = 0; dd < 4; ++dd)
                #pragma unroll
                for (int k = 0; k < 8; ++k)
                    w[dd][k] = Wr2[(d+dd)*DIMD + c0 + 32*k];
            #pragma unroll
            for (int j = 0; j < 4; ++j) {
                const float4 rv = *(const float4*)&sR[rg*4+j][d];
                #pragma unroll
                for (int k = 0; k < 8; ++k)
                    acc[k][j] += rv.x*w[0][k] + rv.y*w[1][k] + rv.z*w[2][k] + rv.w*w[3][k];
            }
        }
        #pragma unroll
        for (int j = 0; j < 4; ++j)
            #pragma unroll
            for (int k = 0; k < 8; ++k)
                out[(size_t)(base + rg*4 + j)*DIMD + c0 + 32*k] = acc[k][j];
    }
}

// ---------------------------------------------------------------------------
extern "C" void kernel_launch(void* const* d_in, const int* in_sizes, int n_in,
                              void* d_out, int out_size, void* d_ws, size_t ws_size,
                              hipStream_t stream)
{
    (void)in_sizes; (void)n_in; (void)out_size; (void)ws_size;
    const float* obs  = (const float*)d_in[0];
    const float* W1   = (const float*)d_in[1];
    const float* b1   = (const float*)d_in[2];
    const float* W2   = (const float*)d_in[3];
    const float* b2   = (const float*)d_in[4];
    const float* Wc   = (const float*)d_in[5];
    const float* bc   = (const float*)d_in[6];
    const float* Wd   = (const float*)d_in[7];
    const float* bd   = (const float*)d_in[8];
    const float* Wbil = (const float*)d_in[9];
    const float* bbil = (const float*)d_in[10];
    const float* Wr1  = (const float*)d_in[11];
    const float* br1  = (const float*)d_in[12];
    const float* Wr2  = (const float*)d_in[13];
    const float* br2  = (const float*)d_in[14];
    float* outp = (float*)d_out;

    float* msgs = (float*)d_ws;                 // BN*64 floats = 8.4 MB
    float* aggp = msgs + (size_t)BN * MSG;      // BN*64 floats = 8.4 MB

    send_k<<<BN/32, 256, 0, stream>>>(obs, W1, b1, W2, b2, Wc, bc, Wd, bd, msgs);
    rel_k <<<BB*8,  256, 0, stream>>>(obs, Wbil, bbil, msgs, aggp);
    recv_k<<<BN/32, 256, 0, stream>>>(obs, aggp, Wr1, br1, Wr2, br2, outp);
}

// Round 2
// 585.131 us; speedup vs baseline: 1.2085x; 1.2085x over previous
//
#include <hip/hip_runtime.h>
#include <cstddef>

// Problem constants
#define BB   128
#define NN   256
#define DIMD 256
#define MSG  64
#define CDIM 32
#define TOPK 8
#define H1D  128
#define H2D  256
#define BN   (BB*NN)   // 32768 rows

// ---------------------------------------------------------------------------
// Kernel T: per-batch transpose obs (N x D) -> obsT (D x N), 64x64 tiles.
// ---------------------------------------------------------------------------
__global__ __launch_bounds__(256) void trans_k(
    const float* __restrict__ obs, float* __restrict__ obsT)
{
    __shared__ float s[64][65];
    const int bid = blockIdx.x;          // BB * 16
    const int b  = bid >> 4;
    const int jt = (bid >> 2) & 3;
    const int dt = bid & 3;
    const float* src = obs  + ((size_t)b*NN + jt*64)*DIMD + dt*64;
    float*       dst = obsT + ((size_t)b*DIMD + dt*64)*NN + jt*64;
    const int t = threadIdx.x;
    #pragma unroll
    for (int q = 0; q < 4; ++q) {
        const int idx = t + 256*q;       // 0..1023 float4 slots
        const int r = idx >> 4, c4 = idx & 15;
        const float4 v = *(const float4*)(src + (size_t)r*DIMD + c4*4);
        s[r][c4*4+0]=v.x; s[r][c4*4+1]=v.y; s[r][c4*4+2]=v.z; s[r][c4*4+3]=v.w;
    }
    __syncthreads();
    #pragma unroll
    for (int q = 0; q < 4; ++q) {
        const int idx = t + 256*q;
        const int r = idx >> 4, c4 = idx & 15;   // r = d-row of output
        float4 v;
        v.x = s[c4*4+0][r]; v.y = s[c4*4+1][r];
        v.z = s[c4*4+2][r]; v.w = s[c4*4+3][r];
        *(float4*)(dst + (size_t)r*NN + c4*4) = v;
    }
}

// ---------------------------------------------------------------------------
// Kernel A: send pipeline  obs(256) -> relu h(128) -> full_msg(64) -> comp(32)
//           -> msgs(64).  32 rows/block, 256 threads.
// ---------------------------------------------------------------------------
__global__ __launch_bounds__(256) void send_k(
    const float* __restrict__ obs,
    const float* __restrict__ W1, const float* __restrict__ b1,
    const float* __restrict__ W2, const float* __restrict__ b2,
    const float* __restrict__ Wc, const float* __restrict__ bc,
    const float* __restrict__ Wd, const float* __restrict__ bd,
    float* __restrict__ msgs)
{
    __shared__ __align__(16) float s_obs[32][256];
    __shared__ __align__(16) float s_h [32][128];
    __shared__ __align__(16) float s_fm[32][64];
    __shared__ __align__(16) float s_cp[32][32];
    const int t = threadIdx.x;
    const int base = blockIdx.x * 32;

    {
        const float4* src = (const float4*)(obs + (size_t)base * DIMD);
        float4* dst = (float4*)(&s_obs[0][0]);
        #pragma unroll
        for (int q = 0; q < 8; ++q) dst[t + 256*q] = src[t + 256*q];
    }
    __syncthreads();

    // L1: 256 -> 128
    {
        const int c0 = t & 31;
        const int rg = t >> 5;
        float acc[4][4];
        #pragma unroll
        for (int k = 0; k < 4; ++k) {
            const float bv = b1[c0 + 32*k];
            #pragma unroll
            for (int j = 0; j < 4; ++j) acc[k][j] = bv;
        }
        for (int d = 0; d < 256; d += 4) {
            float w[4][4];
            #pragma unroll
            for (int dd = 0; dd < 4; ++dd)
                #pragma unroll
                for (int k = 0; k < 4; ++k)
                    w[dd][k] = W1[(d+dd)*H1D + c0 + 32*k];
            #pragma unroll
            for (int j = 0; j < 4; ++j) {
                const float4 o = *(const float4*)&s_obs[rg*4+j][d];
                #pragma unroll
                for (int k = 0; k < 4; ++k)
                    acc[k][j] += o.x*w[0][k] + o.y*w[1][k] + o.z*w[2][k] + o.w*w[3][k];
            }
        }
        #pragma unroll
        for (int k = 0; k < 4; ++k)
            #pragma unroll
            for (int j = 0; j < 4; ++j)
                s_h[rg*4+j][c0 + 32*k] = fmaxf(acc[k][j], 0.0f);
    }
    __syncthreads();

    // L2: 128 -> 64
    {
        const int c0 = t & 15;
        const int r0 = (t >> 4) * 2;
        float acc[4][2];
        #pragma unroll
        for (int k = 0; k < 4; ++k) {
            const float bv = b2[c0 + 16*k];
            acc[k][0] = bv; acc[k][1] = bv;
        }
        for (int d = 0; d < 128; d += 4) {
            float w[4][4];
            #pragma unroll
            for (int dd = 0; dd < 4; ++dd)
                #pragma unroll
                for (int k = 0; k < 4; ++k)
                    w[dd][k] = W2[(d+dd)*MSG + c0 + 16*k];
            #pragma unroll
            for (int j = 0; j < 2; ++j) {
                const float4 h = *(const float4*)&s_h[r0+j][d];
                #pragma unroll
                for (int k = 0; k < 4; ++k)
                    acc[k][j] += h.x*w[0][k] + h.y*w[1][k] + h.z*w[2][k] + h.w*w[3][k];
            }
        }
        #pragma unroll
        for (int k = 0; k < 4; ++k)
            #pragma unroll
            for (int j = 0; j < 2; ++j)
                s_fm[r0+j][c0 + 16*k] = acc[k][j];
    }
    __syncthreads();

    // L3: 64 -> 32
    {
        const int c0 = t & 15;
        const int r0 = (t >> 4) * 2;
        float acc[2][2];
        #pragma unroll
        for (int k = 0; k < 2; ++k) {
            const float bv = bc[c0 + 16*k];
            acc[k][0] = bv; acc[k][1] = bv;
        }
        for (int d = 0; d < 64; d += 4) {
            float w[4][2];
            #pragma unroll
            for (int dd = 0; dd < 4; ++dd)
                #pragma unroll
                for (int k = 0; k < 2; ++k)
                    w[dd][k] = Wc[(d+dd)*CDIM + c0 + 16*k];
            #pragma unroll
            for (int j = 0; j < 2; ++j) {
                const float4 h = *(const float4*)&s_fm[r0+j][d];
                #pragma unroll
                for (int k = 0; k < 2; ++k)
                    acc[k][j] += h.x*w[0][k] + h.y*w[1][k] + h.z*w[2][k] + h.w*w[3][k];
            }
        }
        #pragma unroll
        for (int k = 0; k < 2; ++k)
            #pragma unroll
            for (int j = 0; j < 2; ++j)
                s_cp[r0+j][c0 + 16*k] = acc[k][j];
    }
    __syncthreads();

    // L4: 32 -> 64 (decompress), write msgs
    {
        const int c0 = t & 15;
        const int r0 = (t >> 4) * 2;
        float acc[4][2];
        #pragma unroll
        for (int k = 0; k < 4; ++k) {
            const float bv = bd[c0 + 16*k];
            acc[k][0] = bv; acc[k][1] = bv;
        }
        for (int d = 0; d < 32; d += 4) {
            float w[4][4];
            #pragma unroll
            for (int dd = 0; dd < 4; ++dd)
                #pragma unroll
                for (int k = 0; k < 4; ++k)
                    w[dd][k] = Wd[(d+dd)*MSG + c0 + 16*k];
            #pragma unroll
            for (int j = 0; j < 2; ++j) {
                const float4 h = *(const float4*)&s_cp[r0+j][d];
                #pragma unroll
                for (int k = 0; k < 4; ++k)
                    acc[k][j] += h.x*w[0][k] + h.y*w[1][k] + h.z*w[2][k] + h.w*w[3][k];
            }
        }
        #pragma unroll
        for (int j = 0; j < 2; ++j)
            #pragma unroll
            for (int k = 0; k < 4; ++k)
                msgs[(size_t)(base + r0 + j)*MSG + c0 + 16*k] = acc[k][j];
    }
}

// ---------------------------------------------------------------------------
// Kernel B: bilinear relevance + top-k softmax gating + message aggregation.
//   Phase 3 reads obsT (coalesced, like phase 2 reads Wbil). If obsT==null
//   (workspace too small), falls back to uncoalesced direct reads.
// ---------------------------------------------------------------------------
__global__ __launch_bounds__(256) void rel_k(
    const float* __restrict__ obs, const float* __restrict__ obsT,
    const float* __restrict__ Wbil, const float* __restrict__ bbil,
    const float* __restrict__ msgs, float* __restrict__ agg)
{
    __shared__ __align__(16) float sX[32][256];   // obs_i tile, later scores
    __shared__ __align__(16) float sT[32][256];   // tmp tile
    const int t  = threadIdx.x;
    const int b  = blockIdx.x >> 3;
    const int ib = (blockIdx.x & 7) * 32;
    const float* obs_b = obs + (size_t)b * NN * DIMD;

    {
        const float4* src = (const float4*)(obs_b + (size_t)ib * DIMD);
        float4* dst = (float4*)(&sX[0][0]);
        #pragma unroll
        for (int q = 0; q < 8; ++q) dst[t + 256*q] = src[t + 256*q];
    }
    __syncthreads();

    const int c0 = t & 31;
    const int rg = t >> 5;

    // phase 2: tmp[r][c] = sum_d obs_i[r][d] * Wbil[d][c]
    {
        float acc[8][4];
        #pragma unroll
        for (int k = 0; k < 8; ++k)
            #pragma unroll
            for (int j = 0; j < 4; ++j) acc[k][j] = 0.0f;
        for (int d = 0; d < 256; d += 4) {
            float w[4][8];
            #pragma unroll
            for (int dd = 0; dd < 4; ++dd)
                #pragma unroll
                for (int k = 0; k < 8; ++k)
                    w[dd][k] = Wbil[(d+dd)*DIMD + c0 + 32*k];
            #pragma unroll
            for (int j = 0; j < 4; ++j) {
                const float4 o = *(const float4*)&sX[rg*4+j][d];
                #pragma unroll
                for (int k = 0; k < 8; ++k)
                    acc[k][j] += o.x*w[0][k] + o.y*w[1][k] + o.z*w[2][k] + o.w*w[3][k];
            }
        }
        #pragma unroll
        for (int k = 0; k < 8; ++k)
            #pragma unroll
            for (int j = 0; j < 4; ++j)
                sT[rg*4+j][c0 + 32*k] = acc[k][j];
    }
    __syncthreads();

    // phase 3: S[r][c] = sum_d tmp[r][d] * obs_b[c][d] + bbil
    {
        const float bb = bbil[0];
        float acc[8][4];
        #pragma unroll
        for (int k = 0; k < 8; ++k)
            #pragma unroll
            for (int j = 0; j < 4; ++j) acc[k][j] = 0.0f;
        if (obsT != nullptr) {
            // coalesced: obsT_b[d][c]
            const float* oT = obsT + (size_t)b * DIMD * NN;
            for (int d = 0; d < 256; d += 4) {
                float w[4][8];
                #pragma unroll
                for (int dd = 0; dd < 4; ++dd)
                    #pragma unroll
                    for (int k = 0; k < 8; ++k)
                        w[dd][k] = oT[(size_t)(d+dd)*NN + c0 + 32*k];
                #pragma unroll
                for (int j = 0; j < 4; ++j) {
                    const float4 tv = *(const float4*)&sT[rg*4+j][d];
                    #pragma unroll
                    for (int k = 0; k < 8; ++k)
                        acc[k][j] += tv.x*w[0][k] + tv.y*w[1][k] + tv.z*w[2][k] + tv.w*w[3][k];
                }
            }
        } else {
            for (int d = 0; d < 256; d += 4) {
                float4 ov[8];
                #pragma unroll
                for (int k = 0; k < 8; ++k)
                    ov[k] = *(const float4*)&obs_b[(size_t)(c0 + 32*k)*DIMD + d];
                #pragma unroll
                for (int j = 0; j < 4; ++j) {
                    const float4 tv = *(const float4*)&sT[rg*4+j][d];
                    #pragma unroll
                    for (int k = 0; k < 8; ++k)
                        acc[k][j] += tv.x*ov[k].x + tv.y*ov[k].y + tv.z*ov[k].z + tv.w*ov[k].w;
                }
            }
        }
        __syncthreads();   // sX (obs tile) fully consumed before overwrite
        #pragma unroll
        for (int k = 0; k < 8; ++k)
            #pragma unroll
            for (int j = 0; j < 4; ++j)
                sX[rg*4+j][c0 + 32*k] = acc[k][j] + bb;
    }
    __syncthreads();

    // phase 4: per-row top-8 (lowest-index tie-break), softmax, gather msgs
    {
        const int wave = t >> 6;
        const int lane = t & 63;
        for (int rr = 0; rr < 8; ++rr) {
            const int r = wave * 8 + rr;
            float v[4];
            #pragma unroll
            for (int q = 0; q < 4; ++q) v[q] = sX[r][lane + 64*q];

            float topv[TOPK]; int topi[TOPK];
            #pragma unroll
            for (int k = 0; k < TOPK; ++k) {
                float bv = -3.4028235e38f; int bi = 1 << 30;
                #pragma unroll
                for (int q = 0; q < 4; ++q) {
                    const int id = lane + 64*q;
                    bool excl = false;
                    #pragma unroll
                    for (int kk = 0; kk < TOPK; ++kk)
                        if (kk < k && topi[kk] == id) excl = true;
                    if (!excl && v[q] > bv) { bv = v[q]; bi = id; }
                }
                #pragma unroll
                for (int off = 32; off > 0; off >>= 1) {
                    const float ovv = __shfl_xor(bv, off);
                    const int   oii = __shfl_xor(bi, off);
                    if (ovv > bv || (ovv == bv && oii < bi)) { bv = ovv; bi = oii; }
                }
                topv[k] = bv; topi[k] = bi;
            }

            float e[TOPK]; float ssum = 0.0f;
            #pragma unroll
            for (int k = 0; k < TOPK; ++k) { e[k] = __expf(topv[k] - topv[0]); ssum += e[k]; }
            const float inv = 1.0f / ssum;

            float a = 0.0f;
            #pragma unroll
            for (int k = 0; k < TOPK; ++k)
                a = fmaf(e[k] * inv, msgs[(size_t)(b*NN + topi[k])*MSG + lane], a);
            agg[(size_t)(b*NN + ib + r)*MSG + lane] = a;
        }
    }
}

// ---------------------------------------------------------------------------
// Kernel C: receiver MLP  [obs(256), agg(64)](320) -> relu(256) -> out(256)
// ---------------------------------------------------------------------------
__global__ __launch_bounds__(256) void recv_k(
    const float* __restrict__ obs, const float* __restrict__ agg,
    const float* __restrict__ Wr1, const float* __restrict__ br1,
    const float* __restrict__ Wr2, const float* __restrict__ br2,
    float* __restrict__ out)
{
    __shared__ __align__(16) float sC[32][320];
    __shared__ __align__(16) float sR[32][256];
    const int t = threadIdx.x;
    const int base = blockIdx.x * 32;

    {
        const float4* so = (const float4*)(obs + (size_t)base * DIMD);
        #pragma unroll
        for (int q = 0; q < 8; ++q) {
            const int idx = t + 256*q;
            const int r = idx >> 6, c4 = idx & 63;
            *(float4*)&sC[r][c4*4] = so[idx];
        }
        const float4* sa = (const float4*)(agg + (size_t)base * MSG);
        #pragma unroll
        for (int q = 0; q < 2; ++q) {
            const int idx = t + 256*q;
            const int r = idx >> 4, c4 = idx & 15;
            *(float4*)&sC[r][256 + c4*4] = sa[idx];
        }
    }
    __syncthreads();

    const int c0 = t & 31;
    const int rg = t >> 5;

    // L1: 320 -> 256, relu
    {
        float acc[8][4];
        #pragma unroll
        for (int k = 0; k < 8; ++k) {
            const float bv = br1[c0 + 32*k];
            #pragma unroll
            for (int j = 0; j < 4; ++j) acc[k][j] = bv;
        }
        for (int d = 0; d < 320; d += 4) {
            float w[4][8];
            #pragma unroll
            for (int dd = 0; dd < 4; ++dd)
                #pragma unroll
                for (int k = 0; k < 8; ++k)
                    w[dd][k] = Wr1[(d+dd)*H2D + c0 + 32*k];
            #pragma unroll
            for (int j = 0; j < 4; ++j) {
                const float4 cc = *(const float4*)&sC[rg*4+j][d];
                #pragma unroll
                for (int k = 0; k < 8; ++k)
                    acc[k][j] += cc.x*w[0][k] + cc.y*w[1][k] + cc.z*w[2][k] + cc.w*w[3][k];
            }
        }
        #pragma unroll
        for (int k = 0; k < 8; ++k)
            #pragma unroll
            for (int j = 0; j < 4; ++j)
                sR[rg*4+j][c0 + 32*k] = fmaxf(acc[k][j], 0.0f);
    }
    __syncthreads();

    // L2: 256 -> 256, write out
    {
        float acc[8][4];
        #pragma unroll
        for (int k = 0; k < 8; ++k) {
            const float bv = br2[c0 + 32*k];
            #pragma unroll
            for (int j = 0; j < 4; ++j) acc[k][j] = bv;
        }
        for (int d = 0; d < 256; d += 4) {
            float w[4][8];
            #pragma unroll
            for (int dd = 0; dd < 4; ++dd)
                #pragma unroll
                for (int k = 0; k < 8; ++k)
                    w[dd][k] = Wr2[(d+dd)*DIMD + c0 + 32*k];
            #pragma unroll
            for (int j = 0; j < 4; ++j) {
                const float4 rv = *(const float4*)&sR[rg*4+j][d];
                #pragma unroll
                for (int k = 0; k < 8; ++k)
                    acc[k][j] += rv.x*w[0][k] + rv.y*w[1][k] + rv.z*w[2][k] + rv.w*w[3][k];
            }
        }
        #pragma unroll
        for (int j = 0; j < 4; ++j)
            #pragma unroll
            for (int k = 0; k < 8; ++k)
                out[(size_t)(base + rg*4 + j)*DIMD + c0 + 32*k] = acc[k][j];
    }
}

// ---------------------------------------------------------------------------
extern "C" void kernel_launch(void* const* d_in, const int* in_sizes, int n_in,
                              void* d_out, int out_size, void* d_ws, size_t ws_size,
                              hipStream_t stream)
{
    (void)in_sizes; (void)n_in; (void)out_size;
    const float* obs  = (const float*)d_in[0];
    const float* W1   = (const float*)d_in[1];
    const float* b1   = (const float*)d_in[2];
    const float* W2   = (const float*)d_in[3];
    const float* b2   = (const float*)d_in[4];
    const float* Wc   = (const float*)d_in[5];
    const float* bc   = (const float*)d_in[6];
    const float* Wd   = (const float*)d_in[7];
    const float* bd   = (const float*)d_in[8];
    const float* Wbil = (const float*)d_in[9];
    const float* bbil = (const float*)d_in[10];
    const float* Wr1  = (const float*)d_in[11];
    const float* br1  = (const float*)d_in[12];
    const float* Wr2  = (const float*)d_in[13];
    const float* br2  = (const float*)d_in[14];
    float* outp = (float*)d_out;

    float* msgs = (float*)d_ws;                       // 8 MB
    float* aggp = msgs + (size_t)BN * MSG;            // 8 MB
    float* obsT = aggp + (size_t)BN * MSG;            // 32 MB (optional)
    const size_t need = ((size_t)BN*MSG*2 + (size_t)BB*DIMD*NN) * sizeof(float);
    const bool useT = (ws_size >= need);

    send_k<<<BN/32, 256, 0, stream>>>(obs, W1, b1, W2, b2, Wc, bc, Wd, bd, msgs);
    if (useT)
        trans_k<<<BB*16, 256, 0, stream>>>(obs, obsT);
    rel_k <<<BB*8,  256, 0, stream>>>(obs, useT ? obsT : nullptr, Wbil, bbil, msgs, aggp);
    recv_k<<<BN/32, 256, 0, stream>>>(obs, aggp, Wr1, br1, Wr2, br2, outp);
}

// Round 3
// 362.788 us; speedup vs baseline: 1.9492x; 1.6129x over previous
//
#include <hip/hip_runtime.h>
#include <cstddef>

// Problem constants
#define BB   128
#define NN   256
#define DIMD 256
#define MSG  64
#define CDIM 32
#define TOPK 8
#define H1D  128
#define H2D  256
#define BN   (BB*NN)   // 32768 rows

typedef unsigned short u16;
typedef u16   u16x4  __attribute__((ext_vector_type(4)));
typedef short short8 __attribute__((ext_vector_type(8)));
typedef float f32x4  __attribute__((ext_vector_type(4)));

__device__ __forceinline__ u16 f2bf(float f) {
    // round-half-up bf16: 2 VALU ops, error <= ~0.5 ulp (vs RNE) — fine at our margin
    return (u16)((__float_as_uint(f) + 0x8000u) >> 16);
}
__device__ __forceinline__ float bf2f(u16 u) {
    return __uint_as_float(((unsigned)u) << 16);
}
#define MFMA16(a,b,c) __builtin_amdgcn_mfma_f32_16x16x32_bf16((a),(b),(c),0,0,0)

// ---------------------------------------------------------------------------
// prep: obs fp32 -> bf16 (row-major, unchanged layout)
// ---------------------------------------------------------------------------
__global__ __launch_bounds__(256) void conv_obs_k(
    const float* __restrict__ obs, u16* __restrict__ obs_bf)
{
    const int i = (blockIdx.x * 256 + threadIdx.x) * 4;   // BN*256 total
    const float4 v = *(const float4*)(obs + i);
    u16x4 o;
    o[0] = f2bf(v.x); o[1] = f2bf(v.y); o[2] = f2bf(v.z); o[3] = f2bf(v.w);
    *(u16x4*)(obs_bf + i) = o;
}

// ---------------------------------------------------------------------------
// prep: all weights fp32 [in][out] -> bf16 [out][in]  (B^T layout for MFMA)
// 258048 threads exactly; coalesced reads, scattered bf16 writes (tiny).
// ---------------------------------------------------------------------------
__global__ __launch_bounds__(256) void prep_w_k(
    const float* __restrict__ W1, const float* __restrict__ W2,
    const float* __restrict__ Wc, const float* __restrict__ Wd,
    const float* __restrict__ Wb, const float* __restrict__ Wr1,
    const float* __restrict__ Wr2,
    u16* __restrict__ Wt1, u16* __restrict__ Wt2, u16* __restrict__ Wtc,
    u16* __restrict__ Wtd, u16* __restrict__ WtB, u16* __restrict__ Wtr1,
    u16* __restrict__ Wtr2)
{
    const int t = blockIdx.x * 256 + threadIdx.x;
    const float* src; u16* dst; int I, os, loc;
    if      (t <  32768) { src = W1;  dst = Wt1;  I = 256; os = 7; loc = t; }
    else if (t <  40960) { src = W2;  dst = Wt2;  I = 128; os = 6; loc = t - 32768; }
    else if (t <  43008) { src = Wc;  dst = Wtc;  I = 64;  os = 5; loc = t - 40960; }
    else if (t <  45056) { src = Wd;  dst = Wtd;  I = 32;  os = 6; loc = t - 43008; }
    else if (t < 110592) { src = Wb;  dst = WtB;  I = 256; os = 8; loc = t - 45056; }
    else if (t < 192512) { src = Wr1; dst = Wtr1; I = 320; os = 8; loc = t - 110592; }
    else                 { src = Wr2; dst = Wtr2; I = 256; os = 8; loc = t - 192512; }
    const int i = loc >> os;                 // input-dim index
    const int o = loc & ((1 << os) - 1);     // output-dim index
    dst[(size_t)o * I + i] = f2bf(src[loc]);
}

// ---------------------------------------------------------------------------
// send: obs(256) -> relu h(128) -> fm(64) -> cp(32) -> msgs(64), bf16 MFMA.
// 64 rows/block, 4 waves, wave-private 16-row m-tile. No barriers.
// ---------------------------------------------------------------------------
__global__ __launch_bounds__(256) void send_k2(
    const u16* __restrict__ obs_bf,
    const u16* __restrict__ Wt1, const float* __restrict__ b1,
    const u16* __restrict__ Wt2, const float* __restrict__ b2,
    const u16* __restrict__ Wtc, const float* __restrict__ bc,
    const u16* __restrict__ Wtd, const float* __restrict__ bd,
    u16* __restrict__ msgs_bf)
{
    __shared__ u16 sH[64][136];   // stride 272B = 68 dw = 4 mod 32 -> 2-way (free)
    __shared__ u16 sF[64][72];    // 144B = 36 dw = 4 mod 32
    __shared__ u16 sC[64][40];    // 80B = 20 dw -> 2-way
    const int t = threadIdx.x;
    const int w = t >> 6, l = t & 63, q = l >> 4, ls = l & 15;
    const int row0 = blockIdx.x * 64 + w * 16;
    const int lr0  = w * 16;   // local LDS row base (wave-private)

    // L1: 256 -> 128, relu
    {
        f32x4 acc[8];
        #pragma unroll
        for (int n = 0; n < 8; ++n) acc[n] = (f32x4){0,0,0,0};
        #pragma unroll
        for (int kk = 0; kk < 8; ++kk) {
            const int k0 = kk * 32;
            const short8 a = *(const short8*)(obs_bf + (size_t)(row0 + ls)*256 + k0 + q*8);
            #pragma unroll
            for (int n = 0; n < 8; ++n) {
                const short8 bfr = *(const short8*)(Wt1 + (size_t)(n*16 + ls)*256 + k0 + q*8);
                acc[n] = MFMA16(a, bfr, acc[n]);
            }
        }
        #pragma unroll
        for (int n = 0; n < 8; ++n) {
            const float bv = b1[n*16 + ls];
            #pragma unroll
            for (int r = 0; r < 4; ++r)
                sH[lr0 + q*4 + r][n*16 + ls] = f2bf(fmaxf(acc[n][r] + bv, 0.0f));
        }
    }
    // L2: 128 -> 64
    {
        f32x4 acc[4];
        #pragma unroll
        for (int n = 0; n < 4; ++n) acc[n] = (f32x4){0,0,0,0};
        #pragma unroll
        for (int kk = 0; kk < 4; ++kk) {
            const int k0 = kk * 32;
            const short8 a = *(const short8*)(&sH[lr0 + ls][k0 + q*8]);
            #pragma unroll
            for (int n = 0; n < 4; ++n) {
                const short8 bfr = *(const short8*)(Wt2 + (size_t)(n*16 + ls)*128 + k0 + q*8);
                acc[n] = MFMA16(a, bfr, acc[n]);
            }
        }
        #pragma unroll
        for (int n = 0; n < 4; ++n) {
            const float bv = b2[n*16 + ls];
            #pragma unroll
            for (int r = 0; r < 4; ++r)
                sF[lr0 + q*4 + r][n*16 + ls] = f2bf(acc[n][r] + bv);
        }
    }
    // L3: 64 -> 32
    {
        f32x4 acc[2];
        acc[0] = (f32x4){0,0,0,0}; acc[1] = (f32x4){0,0,0,0};
        #pragma unroll
        for (int kk = 0; kk < 2; ++kk) {
            const int k0 = kk * 32;
            const short8 a = *(const short8*)(&sF[lr0 + ls][k0 + q*8]);
            #pragma unroll
            for (int n = 0; n < 2; ++n) {
                const short8 bfr = *(const short8*)(Wtc + (size_t)(n*16 + ls)*64 + k0 + q*8);
                acc[n] = MFMA16(a, bfr, acc[n]);
            }
        }
        #pragma unroll
        for (int n = 0; n < 2; ++n) {
            const float bv = bc[n*16 + ls];
            #pragma unroll
            for (int r = 0; r < 4; ++r)
                sC[lr0 + q*4 + r][n*16 + ls] = f2bf(acc[n][r] + bv);
        }
    }
    // L4: 32 -> 64, write msgs (bf16)
    {
        f32x4 acc[4];
        #pragma unroll
        for (int n = 0; n < 4; ++n) acc[n] = (f32x4){0,0,0,0};
        const short8 a = *(const short8*)(&sC[lr0 + ls][q*8]);
        #pragma unroll
        for (int n = 0; n < 4; ++n) {
            const short8 bfr = *(const short8*)(Wtd + (size_t)(n*16 + ls)*32 + q*8);
            acc[n] = MFMA16(a, bfr, acc[n]);
        }
        #pragma unroll
        for (int n = 0; n < 4; ++n) {
            const float bv = bd[n*16 + ls];
            #pragma unroll
            for (int r = 0; r < 4; ++r)
                msgs_bf[(size_t)(row0 + q*4 + r)*MSG + n*16 + ls] = f2bf(acc[n][r] + bv);
        }
    }
}

// ---------------------------------------------------------------------------
// rel: tmp = obs_i @ Wbil ; scores = tmp @ obs_b^T + bbil ; top-8 softmax
//      gather of msgs. 32 rows/block, 2 waves, wave-private. No barriers.
// ---------------------------------------------------------------------------
__global__ __launch_bounds__(128) void rel_k2(
    const u16* __restrict__ obs_bf, const u16* __restrict__ WtB,
    const float* __restrict__ bbil, const u16* __restrict__ msgs_bf,
    u16* __restrict__ agg_bf)
{
    __shared__ u16 sT[32][264];   // tmp (bf16), stride 528B = 33*16 aligned
    __shared__ u16 sS[32][264];   // scores (bf16)
    const int t = threadIdx.x;
    const int w = t >> 6, l = t & 63, q = l >> 4, ls = l & 15;
    const int b  = blockIdx.x >> 3;
    const int ib = (blockIdx.x & 7) * 32;
    const int row0 = b * NN + ib + w * 16;   // global obs row of this wave's m-tile
    const int lr0  = w * 16;

    // phase 2: tmp[m][e] = sum_d obs[m][d] * Wbil[d][e]
    {
        f32x4 acc[16];
        #pragma unroll
        for (int n = 0; n < 16; ++n) acc[n] = (f32x4){0,0,0,0};
        #pragma unroll
        for (int kk = 0; kk < 8; ++kk) {
            const int k0 = kk * 32;
            const short8 a = *(const short8*)(obs_bf + (size_t)(row0 + ls)*256 + k0 + q*8);
            #pragma unroll
            for (int n = 0; n < 16; ++n) {
                const short8 bfr = *(const short8*)(WtB + (size_t)(n*16 + ls)*256 + k0 + q*8);
                acc[n] = MFMA16(a, bfr, acc[n]);
            }
        }
        #pragma unroll
        for (int n = 0; n < 16; ++n)
            #pragma unroll
            for (int r = 0; r < 4; ++r)
                sT[lr0 + q*4 + r][n*16 + ls] = f2bf(acc[n][r]);
    }
    // phase 3: scores[m][j] = sum_e tmp[m][e] * obs_b[j][e] + bbil
    {
        const float bb = bbil[0];
        f32x4 acc[16];
        #pragma unroll
        for (int n = 0; n < 16; ++n) acc[n] = (f32x4){0,0,0,0};
        #pragma unroll
        for (int kk = 0; kk < 8; ++kk) {
            const int k0 = kk * 32;
            const short8 a = *(const short8*)(&sT[lr0 + ls][k0 + q*8]);
            #pragma unroll
            for (int n = 0; n < 16; ++n) {
                const short8 bfr = *(const short8*)(obs_bf + (size_t)(b*NN + n*16 + ls)*256 + k0 + q*8);
                acc[n] = MFMA16(a, bfr, acc[n]);
            }
        }
        #pragma unroll
        for (int n = 0; n < 16; ++n)
            #pragma unroll
            for (int r = 0; r < 4; ++r)
                sS[lr0 + q*4 + r][n*16 + ls] = f2bf(acc[n][r] + bb);
    }
    // phase 4: per-row top-8 (lowest-index tie-break), softmax, gather msgs
    {
        for (int rr = 0; rr < 16; ++rr) {
            const int r = lr0 + rr;
            float v[4];
            #pragma unroll
            for (int qq = 0; qq < 4; ++qq) v[qq] = bf2f(sS[r][l + 64*qq]);

            float topv[TOPK]; int topi[TOPK];
            #pragma unroll
            for (int k = 0; k < TOPK; ++k) {
                float bv = -3.4028235e38f; int bi = 1 << 30;
                #pragma unroll
                for (int qq = 0; qq < 4; ++qq) {
                    const int id = l + 64*qq;
                    bool excl = false;
                    #pragma unroll
                    for (int kk = 0; kk < TOPK; ++kk)
                        if (kk < k && topi[kk] == id) excl = true;
                    if (!excl && v[qq] > bv) { bv = v[qq]; bi = id; }
                }
                #pragma unroll
                for (int off = 32; off > 0; off >>= 1) {
                    const float ovv = __shfl_xor(bv, off);
                    const int   oii = __shfl_xor(bi, off);
                    if (ovv > bv || (ovv == bv && oii < bi)) { bv = ovv; bi = oii; }
                }
                topv[k] = bv; topi[k] = bi;
            }

            float e[TOPK]; float ssum = 0.0f;
            #pragma unroll
            for (int k = 0; k < TOPK; ++k) { e[k] = __expf(topv[k] - topv[0]); ssum += e[k]; }
            const float inv = 1.0f / ssum;

            float a = 0.0f;
            #pragma unroll
            for (int k = 0; k < TOPK; ++k)
                a = fmaf(e[k] * inv, bf2f(msgs_bf[(size_t)(b*NN + topi[k])*MSG + l]), a);
            agg_bf[(size_t)(b*NN + ib + r)*MSG + l] = f2bf(a);
        }
    }
}

// ---------------------------------------------------------------------------
// recv: [obs(256)|agg(64)](K=320) -> relu(256) -> out(256), bf16 MFMA.
// 64 rows/block, 4 waves, wave-private. No barriers. fp32 output.
// ---------------------------------------------------------------------------
__global__ __launch_bounds__(256) void recv_k2(
    const u16* __restrict__ obs_bf, const u16* __restrict__ agg_bf,
    const u16* __restrict__ Wtr1, const float* __restrict__ br1,
    const u16* __restrict__ Wtr2, const float* __restrict__ br2,
    float* __restrict__ out)
{
    __shared__ u16 sR[64][264];
    const int t = threadIdx.x;
    const int w = t >> 6, l = t & 63, q = l >> 4, ls = l & 15;
    const int row0 = blockIdx.x * 64 + w * 16;
    const int lr0  = w * 16;

    // L1: K=320 (obs 0..255, agg 256..319) -> 256, relu
    {
        f32x4 acc[16];
        #pragma unroll
        for (int n = 0; n < 16; ++n) acc[n] = (f32x4){0,0,0,0};
        #pragma unroll
        for (int kk = 0; kk < 10; ++kk) {
            const int k0 = kk * 32;
            const u16* ap = (k0 < 256)
                ? obs_bf + (size_t)(row0 + ls)*256 + k0 + q*8
                : agg_bf + (size_t)(row0 + ls)*64  + (k0 - 256) + q*8;
            const short8 a = *(const short8*)ap;
            #pragma unroll
            for (int n = 0; n < 16; ++n) {
                const short8 bfr = *(const short8*)(Wtr1 + (size_t)(n*16 + ls)*320 + k0 + q*8);
                acc[n] = MFMA16(a, bfr, acc[n]);
            }
        }
        #pragma unroll
        for (int n = 0; n < 16; ++n) {
            const float bv = br1[n*16 + ls];
            #pragma unroll
            for (int r = 0; r < 4; ++r)
                sR[lr0 + q*4 + r][n*16 + ls] = f2bf(fmaxf(acc[n][r] + bv, 0.0f));
        }
    }
    // L2: 256 -> 256, fp32 out
    {
        f32x4 acc[16];
        #pragma unroll
        for (int n = 0; n < 16; ++n) acc[n] = (f32x4){0,0,0,0};
        #pragma unroll
        for (int kk = 0; kk < 8; ++kk) {
            const int k0 = kk * 32;
            const short8 a = *(const short8*)(&sR[lr0 + ls][k0 + q*8]);
            #pragma unroll
            for (int n = 0; n < 16; ++n) {
                const short8 bfr = *(const short8*)(Wtr2 + (size_t)(n*16 + ls)*256 + k0 + q*8);
                acc[n] = MFMA16(a, bfr, acc[n]);
            }
        }
        #pragma unroll
        for (int n = 0; n < 16; ++n) {
            const float bv = br2[n*16 + ls];
            #pragma unroll
            for (int r = 0; r < 4; ++r)
                out[(size_t)(row0 + q*4 + r)*DIMD + n*16 + ls] = acc[n][r] + bv;
        }
    }
}

// ---------------------------------------------------------------------------
extern "C" void kernel_launch(void* const* d_in, const int* in_sizes, int n_in,
                              void* d_out, int out_size, void* d_ws, size_t ws_size,
                              hipStream_t stream)
{
    (void)in_sizes; (void)n_in; (void)out_size; (void)ws_size;
    const float* obs  = (const float*)d_in[0];
    const float* W1   = (const float*)d_in[1];
    const float* b1   = (const float*)d_in[2];
    const float* W2   = (const float*)d_in[3];
    const float* b2   = (const float*)d_in[4];
    const float* Wc   = (const float*)d_in[5];
    const float* bc   = (const float*)d_in[6];
    const float* Wd   = (const float*)d_in[7];
    const float* bd   = (const float*)d_in[8];
    const float* Wbil = (const float*)d_in[9];
    const float* bbil = (const float*)d_in[10];
    const float* Wr1  = (const float*)d_in[11];
    const float* br1  = (const float*)d_in[12];
    const float* Wr2  = (const float*)d_in[13];
    const float* br2  = (const float*)d_in[14];
    float* outp = (float*)d_out;

    // workspace layout (bf16 elements), ~25.7 MB total
    u16* obs_bf  = (u16*)d_ws;                 // BN*256 = 8388608
    u16* msgs_bf = obs_bf  + (size_t)BN*256;   // BN*64  = 2097152
    u16* agg_bf  = msgs_bf + (size_t)BN*64;    // BN*64  = 2097152
    u16* Wt1  = agg_bf + (size_t)BN*64;        // 32768
    u16* Wt2  = Wt1  + 32768;                  // 8192
    u16* Wtc  = Wt2  + 8192;                   // 2048
    u16* Wtd  = Wtc  + 2048;                   // 2048
    u16* WtB  = Wtd  + 2048;                   // 65536
    u16* Wtr1 = WtB  + 65536;                  // 81920
    u16* Wtr2 = Wtr1 + 81920;                  // 65536

    conv_obs_k<<<(size_t)BN*256/1024, 256, 0, stream>>>(obs, obs_bf);
    prep_w_k<<<1008, 256, 0, stream>>>(W1, W2, Wc, Wd, Wbil, Wr1, Wr2,
                                       Wt1, Wt2, Wtc, Wtd, WtB, Wtr1, Wtr2);
    send_k2<<<BN/64, 256, 0, stream>>>(obs_bf, Wt1, b1, Wt2, b2, Wtc, bc, Wtd, bd, msgs_bf);
    rel_k2 <<<BB*8, 128, 0, stream>>>(obs_bf, WtB, bbil, msgs_bf, agg_bf);
    recv_k2<<<BN/64, 256, 0, stream>>>(obs_bf, agg_bf, Wtr1, br1, Wtr2, br2, outp);
}

// Round 4
// 320.734 us; speedup vs baseline: 2.2048x; 1.1311x over previous
//
#include <hip/hip_runtime.h>
#include <cstddef>

// Problem constants
#define BB   128
#define NN   256
#define DIMD 256
#define MSG  64
#define CDIM 32
#define TOPK 8
#define H1D  128
#define H2D  256
#define BN   (BB*NN)   // 32768 rows

typedef unsigned short u16;
typedef u16   u16x4  __attribute__((ext_vector_type(4)));
typedef short short8 __attribute__((ext_vector_type(8)));
typedef float f32x4  __attribute__((ext_vector_type(4)));

__device__ __forceinline__ u16 f2bf(float f) {
    return (u16)((__float_as_uint(f) + 0x8000u) >> 16);
}
__device__ __forceinline__ float bf2f(u16 u) {
    return __uint_as_float(((unsigned)u) << 16);
}
#define MFMA16(a,b,c) __builtin_amdgcn_mfma_f32_16x16x32_bf16((a),(b),(c),0,0,0)

// ---------------------------------------------------------------------------
// prep: obs fp32 -> bf16
// ---------------------------------------------------------------------------
__global__ __launch_bounds__(256) void conv_obs_k(
    const float* __restrict__ obs, u16* __restrict__ obs_bf)
{
    const int i = (blockIdx.x * 256 + threadIdx.x) * 4;
    const float4 v = *(const float4*)(obs + i);
    u16x4 o;
    o[0] = f2bf(v.x); o[1] = f2bf(v.y); o[2] = f2bf(v.z); o[3] = f2bf(v.w);
    *(u16x4*)(obs_bf + i) = o;
}

// ---------------------------------------------------------------------------
// prep: all weights fp32 [in][out] -> bf16 [out][in]
// ---------------------------------------------------------------------------
__global__ __launch_bounds__(256) void prep_w_k(
    const float* __restrict__ W1, const float* __restrict__ W2,
    const float* __restrict__ Wc, const float* __restrict__ Wd,
    const float* __restrict__ Wb, const float* __restrict__ Wr1,
    const float* __restrict__ Wr2,
    u16* __restrict__ Wt1, u16* __restrict__ Wt2, u16* __restrict__ Wtc,
    u16* __restrict__ Wtd, u16* __restrict__ WtB, u16* __restrict__ Wtr1,
    u16* __restrict__ Wtr2)
{
    const int t = blockIdx.x * 256 + threadIdx.x;
    const float* src; u16* dst; int I, os, loc;
    if      (t <  32768) { src = W1;  dst = Wt1;  I = 256; os = 7; loc = t; }
    else if (t <  40960) { src = W2;  dst = Wt2;  I = 128; os = 6; loc = t - 32768; }
    else if (t <  43008) { src = Wc;  dst = Wtc;  I = 64;  os = 5; loc = t - 40960; }
    else if (t <  45056) { src = Wd;  dst = Wtd;  I = 32;  os = 6; loc = t - 43008; }
    else if (t < 110592) { src = Wb;  dst = WtB;  I = 256; os = 8; loc = t - 45056; }
    else if (t < 192512) { src = Wr1; dst = Wtr1; I = 320; os = 8; loc = t - 110592; }
    else                 { src = Wr2; dst = Wtr2; I = 256; os = 8; loc = t - 192512; }
    const int i = loc >> os;
    const int o = loc & ((1 << os) - 1);
    dst[(size_t)o * I + i] = f2bf(src[loc]);
}

// ---------------------------------------------------------------------------
// send: obs(256) -> relu h(128) -> fm(64) -> cp(32) -> msgs(64), bf16 MFMA.
// ---------------------------------------------------------------------------
__global__ __launch_bounds__(256) void send_k2(
    const u16* __restrict__ obs_bf,
    const u16* __restrict__ Wt1, const float* __restrict__ b1,
    const u16* __restrict__ Wt2, const float* __restrict__ b2,
    const u16* __restrict__ Wtc, const float* __restrict__ bc,
    const u16* __restrict__ Wtd, const float* __restrict__ bd,
    u16* __restrict__ msgs_bf)
{
    __shared__ u16 sH[64][136];
    __shared__ u16 sF[64][72];
    __shared__ u16 sC[64][40];
    const int t = threadIdx.x;
    const int w = t >> 6, l = t & 63, q = l >> 4, ls = l & 15;
    const int row0 = blockIdx.x * 64 + w * 16;
    const int lr0  = w * 16;

    // L1: 256 -> 128, relu
    {
        f32x4 acc[8];
        #pragma unroll
        for (int n = 0; n < 8; ++n) acc[n] = (f32x4){0,0,0,0};
        #pragma unroll
        for (int kk = 0; kk < 8; ++kk) {
            const int k0 = kk * 32;
            const short8 a = *(const short8*)(obs_bf + (size_t)(row0 + ls)*256 + k0 + q*8);
            #pragma unroll
            for (int n = 0; n < 8; ++n) {
                const short8 bfr = *(const short8*)(Wt1 + (size_t)(n*16 + ls)*256 + k0 + q*8);
                acc[n] = MFMA16(a, bfr, acc[n]);
            }
        }
        #pragma unroll
        for (int n = 0; n < 8; ++n) {
            const float bv = b1[n*16 + ls];
            #pragma unroll
            for (int r = 0; r < 4; ++r)
                sH[lr0 + q*4 + r][n*16 + ls] = f2bf(fmaxf(acc[n][r] + bv, 0.0f));
        }
    }
    // L2: 128 -> 64
    {
        f32x4 acc[4];
        #pragma unroll
        for (int n = 0; n < 4; ++n) acc[n] = (f32x4){0,0,0,0};
        #pragma unroll
        for (int kk = 0; kk < 4; ++kk) {
            const int k0 = kk * 32;
            const short8 a = *(const short8*)(&sH[lr0 + ls][k0 + q*8]);
            #pragma unroll
            for (int n = 0; n < 4; ++n) {
                const short8 bfr = *(const short8*)(Wt2 + (size_t)(n*16 + ls)*128 + k0 + q*8);
                acc[n] = MFMA16(a, bfr, acc[n]);
            }
        }
        #pragma unroll
        for (int n = 0; n < 4; ++n) {
            const float bv = b2[n*16 + ls];
            #pragma unroll
            for (int r = 0; r < 4; ++r)
                sF[lr0 + q*4 + r][n*16 + ls] = f2bf(acc[n][r] + bv);
        }
    }
    // L3: 64 -> 32
    {
        f32x4 acc[2];
        acc[0] = (f32x4){0,0,0,0}; acc[1] = (f32x4){0,0,0,0};
        #pragma unroll
        for (int kk = 0; kk < 2; ++kk) {
            const int k0 = kk * 32;
            const short8 a = *(const short8*)(&sF[lr0 + ls][k0 + q*8]);
            #pragma unroll
            for (int n = 0; n < 2; ++n) {
                const short8 bfr = *(const short8*)(Wtc + (size_t)(n*16 + ls)*64 + k0 + q*8);
                acc[n] = MFMA16(a, bfr, acc[n]);
            }
        }
        #pragma unroll
        for (int n = 0; n < 2; ++n) {
            const float bv = bc[n*16 + ls];
            #pragma unroll
            for (int r = 0; r < 4; ++r)
                sC[lr0 + q*4 + r][n*16 + ls] = f2bf(acc[n][r] + bv);
        }
    }
    // L4: 32 -> 64, write msgs
    {
        f32x4 acc[4];
        #pragma unroll
        for (int n = 0; n < 4; ++n) acc[n] = (f32x4){0,0,0,0};
        const short8 a = *(const short8*)(&sC[lr0 + ls][q*8]);
        #pragma unroll
        for (int n = 0; n < 4; ++n) {
            const short8 bfr = *(const short8*)(Wtd + (size_t)(n*16 + ls)*32 + q*8);
            acc[n] = MFMA16(a, bfr, acc[n]);
        }
        #pragma unroll
        for (int n = 0; n < 4; ++n) {
            const float bv = bd[n*16 + ls];
            #pragma unroll
            for (int r = 0; r < 4; ++r)
                msgs_bf[(size_t)(row0 + q*4 + r)*MSG + n*16 + ls] = f2bf(acc[n][r] + bv);
        }
    }
}

// ---------------------------------------------------------------------------
// rel v3: XCD-swizzled batches, scores reuse sT (LDS halved -> 2x occupancy),
//   top-k: 32 lanes/row, two rows in flight, 5-step butterfly, local-kill.
// ---------------------------------------------------------------------------
__global__ __launch_bounds__(128) void rel_k3(
    const u16* __restrict__ obs_bf, const u16* __restrict__ WtB,
    const float* __restrict__ bbil, const u16* __restrict__ msgs_bf,
    u16* __restrict__ agg_bf)
{
    __shared__ u16 sT[32][264];   // tmp (phase 2/3), then scores (phase 4)
    const int t = threadIdx.x;
    const int w = t >> 6, l = t & 63, q = l >> 4, ls = l & 15;
    const int bid = blockIdx.x;
    // XCD swizzle: all 8 blocks of batch b share bid%8 -> same XCD's L2
    const int b  = (bid & 7) * 16 + (bid >> 6);
    const int ib = ((bid >> 3) & 7) * 32;
    const int row0 = b * NN + ib + w * 16;
    const int lr0  = w * 16;

    // phase 2: tmp[m][e] = sum_d obs[m][d] * Wbil[d][e]
    {
        f32x4 acc[16];
        #pragma unroll
        for (int n = 0; n < 16; ++n) acc[n] = (f32x4){0,0,0,0};
        #pragma unroll
        for (int kk = 0; kk < 8; ++kk) {
            const int k0 = kk * 32;
            const short8 a = *(const short8*)(obs_bf + (size_t)(row0 + ls)*256 + k0 + q*8);
            #pragma unroll
            for (int n = 0; n < 16; ++n) {
                const short8 bfr = *(const short8*)(WtB + (size_t)(n*16 + ls)*256 + k0 + q*8);
                acc[n] = MFMA16(a, bfr, acc[n]);
            }
        }
        #pragma unroll
        for (int n = 0; n < 16; ++n)
            #pragma unroll
            for (int r = 0; r < 4; ++r)
                sT[lr0 + q*4 + r][n*16 + ls] = f2bf(acc[n][r]);
    }
    // phase 3: scores[m][j] = sum_e tmp[m][e] * obs_b[j][e] + bbil
    //   (reads sT as A-fragments, then overwrites sT with scores — DS ops
    //    are in-order per wave and tiles are wave-private, so no barrier)
    {
        const float bb = bbil[0];
        f32x4 acc[16];
        #pragma unroll
        for (int n = 0; n < 16; ++n) acc[n] = (f32x4){0,0,0,0};
        #pragma unroll
        for (int kk = 0; kk < 8; ++kk) {
            const int k0 = kk * 32;
            const short8 a = *(const short8*)(&sT[lr0 + ls][k0 + q*8]);
            #pragma unroll
            for (int n = 0; n < 16; ++n) {
                const short8 bfr = *(const short8*)(obs_bf + (size_t)(b*NN + n*16 + ls)*256 + k0 + q*8);
                acc[n] = MFMA16(a, bfr, acc[n]);
            }
        }
        #pragma unroll
        for (int n = 0; n < 16; ++n)
            #pragma unroll
            for (int r = 0; r < 4; ++r)
                sT[lr0 + q*4 + r][n*16 + ls] = f2bf(acc[n][r] + bb);
    }
    // phase 4: two rows per pass (32 lanes each), top-8 via 5-step butterfly
    {
        const int hl   = l & 31;
        const int half = l >> 5;
        for (int p = 0; p < 8; ++p) {
            const int r = lr0 + p*2 + half;
            float v[8];
            #pragma unroll
            for (int qq = 0; qq < 8; ++qq) v[qq] = bf2f(sT[r][hl + 32*qq]);

            float topv[TOPK]; int topi[TOPK];
            #pragma unroll
            for (int k = 0; k < TOPK; ++k) {
                // local argmax; ascending-index scan with strict > keeps lowest idx
                float bv = v[0]; int bq = 0;
                #pragma unroll
                for (int qq = 1; qq < 8; ++qq)
                    if (v[qq] > bv) { bv = v[qq]; bq = qq; }
                int bi = hl + 32*bq;
                #pragma unroll
                for (int off = 16; off > 0; off >>= 1) {
                    const float ovv = __shfl_xor(bv, off);
                    const int   oii = __shfl_xor(bi, off);
                    if (ovv > bv || (ovv == bv && oii < bi)) { bv = ovv; bi = oii; }
                }
                topv[k] = bv; topi[k] = bi;
                // kill winner locally (predicated, no dynamic reg indexing)
                #pragma unroll
                for (int qq = 0; qq < 8; ++qq)
                    if (bi == hl + 32*qq) v[qq] = -3.4028235e38f;
            }

            float e[TOPK]; float ssum = 0.0f;
            #pragma unroll
            for (int k = 0; k < TOPK; ++k) { e[k] = __expf(topv[k] - topv[0]); ssum += e[k]; }
            const float inv = 1.0f / ssum;

            float a0 = 0.0f, a1 = 0.0f;
            #pragma unroll
            for (int k = 0; k < TOPK; ++k) {
                const float g = e[k] * inv;
                const u16* mp = msgs_bf + (size_t)(b*NN + topi[k])*MSG;
                a0 = fmaf(g, bf2f(mp[hl]),      a0);
                a1 = fmaf(g, bf2f(mp[hl + 32]), a1);
            }
            u16* op = agg_bf + (size_t)(b*NN + ib + r)*MSG;
            op[hl]      = f2bf(a0);
            op[hl + 32] = f2bf(a1);
        }
    }
}

// ---------------------------------------------------------------------------
// recv: [obs(256)|agg(64)](K=320) -> relu(256) -> out(256), bf16 MFMA.
// ---------------------------------------------------------------------------
__global__ __launch_bounds__(256) void recv_k2(
    const u16* __restrict__ obs_bf, const u16* __restrict__ agg_bf,
    const u16* __restrict__ Wtr1, const float* __restrict__ br1,
    const u16* __restrict__ Wtr2, const float* __restrict__ br2,
    float* __restrict__ out)
{
    __shared__ u16 sR[64][264];
    const int t = threadIdx.x;
    const int w = t >> 6, l = t & 63, q = l >> 4, ls = l & 15;
    const int row0 = blockIdx.x * 64 + w * 16;
    const int lr0  = w * 16;

    // L1: K=320 -> 256, relu
    {
        f32x4 acc[16];
        #pragma unroll
        for (int n = 0; n < 16; ++n) acc[n] = (f32x4){0,0,0,0};
        #pragma unroll
        for (int kk = 0; kk < 10; ++kk) {
            const int k0 = kk * 32;
            const u16* ap = (k0 < 256)
                ? obs_bf + (size_t)(row0 + ls)*256 + k0 + q*8
                : agg_bf + (size_t)(row0 + ls)*64  + (k0 - 256) + q*8;
            const short8 a = *(const short8*)ap;
            #pragma unroll
            for (int n = 0; n < 16; ++n) {
                const short8 bfr = *(const short8*)(Wtr1 + (size_t)(n*16 + ls)*320 + k0 + q*8);
                acc[n] = MFMA16(a, bfr, acc[n]);
            }
        }
        #pragma unroll
        for (int n = 0; n < 16; ++n) {
            const float bv = br1[n*16 + ls];
            #pragma unroll
            for (int r = 0; r < 4; ++r)
                sR[lr0 + q*4 + r][n*16 + ls] = f2bf(fmaxf(acc[n][r] + bv, 0.0f));
        }
    }
    // L2: 256 -> 256, fp32 out
    {
        f32x4 acc[16];
        #pragma unroll
        for (int n = 0; n < 16; ++n) acc[n] = (f32x4){0,0,0,0};
        #pragma unroll
        for (int kk = 0; kk < 8; ++kk) {
            const int k0 = kk * 32;
            const short8 a = *(const short8*)(&sR[lr0 + ls][k0 + q*8]);
            #pragma unroll
            for (int n = 0; n < 16; ++n) {
                const short8 bfr = *(const short8*)(Wtr2 + (size_t)(n*16 + ls)*256 + k0 + q*8);
                acc[n] = MFMA16(a, bfr, acc[n]);
            }
        }
        #pragma unroll
        for (int n = 0; n < 16; ++n) {
            const float bv = br2[n*16 + ls];
            #pragma unroll
            for (int r = 0; r < 4; ++r)
                out[(size_t)(row0 + q*4 + r)*DIMD + n*16 + ls] = acc[n][r] + bv;
        }
    }
}

// ---------------------------------------------------------------------------
extern "C" void kernel_launch(void* const* d_in, const int* in_sizes, int n_in,
                              void* d_out, int out_size, void* d_ws, size_t ws_size,
                              hipStream_t stream)
{
    (void)in_sizes; (void)n_in; (void)out_size; (void)ws_size;
    const float* obs  = (const float*)d_in[0];
    const float* W1   = (const float*)d_in[1];
    const float* b1   = (const float*)d_in[2];
    const float* W2   = (const float*)d_in[3];
    const float* b2   = (const float*)d_in[4];
    const float* Wc   = (const float*)d_in[5];
    const float* bc   = (const float*)d_in[6];
    const float* Wd   = (const float*)d_in[7];
    const float* bd   = (const float*)d_in[8];
    const float* Wbil = (const float*)d_in[9];
    const float* bbil = (const float*)d_in[10];
    const float* Wr1  = (const float*)d_in[11];
    const float* br1  = (const float*)d_in[12];
    const float* Wr2  = (const float*)d_in[13];
    const float* br2  = (const float*)d_in[14];
    float* outp = (float*)d_out;

    u16* obs_bf  = (u16*)d_ws;
    u16* msgs_bf = obs_bf  + (size_t)BN*256;
    u16* agg_bf  = msgs_bf + (size_t)BN*64;
    u16* Wt1  = agg_bf + (size_t)BN*64;
    u16* Wt2  = Wt1  + 32768;
    u16* Wtc  = Wt2  + 8192;
    u16* Wtd  = Wtc  + 2048;
    u16* WtB  = Wtd  + 2048;
    u16* Wtr1 = WtB  + 65536;
    u16* Wtr2 = Wtr1 + 81920;

    conv_obs_k<<<(size_t)BN*256/1024, 256, 0, stream>>>(obs, obs_bf);
    prep_w_k<<<1008, 256, 0, stream>>>(W1, W2, Wc, Wd, Wbil, Wr1, Wr2,
                                       Wt1, Wt2, Wtc, Wtd, WtB, Wtr1, Wtr2);
    send_k2<<<BN/64, 256, 0, stream>>>(obs_bf, Wt1, b1, Wt2, b2, Wtc, bc, Wtd, bd, msgs_bf);
    rel_k3 <<<BB*8, 128, 0, stream>>>(obs_bf, WtB, bbil, msgs_bf, agg_bf);
    recv_k2<<<BN/64, 256, 0, stream>>>(obs_bf, agg_bf, Wtr1, br1, Wtr2, br2, outp);
}

// Round 5
// 289.634 us; speedup vs baseline: 2.4415x; 1.1074x over previous
//
#include <hip/hip_runtime.h>
#include <cstddef>

// Problem constants
#define BB   128
#define NN   256
#define DIMD 256
#define MSG  64
#define CDIM 32
#define TOPK 8
#define H1D  128
#define H2D  256
#define BN   (BB*NN)   // 32768 rows

typedef unsigned short u16;
typedef u16   u16x4  __attribute__((ext_vector_type(4)));
typedef u16   u16x8  __attribute__((ext_vector_type(8)));
typedef short short8 __attribute__((ext_vector_type(8)));
typedef float f32x4  __attribute__((ext_vector_type(4)));

__device__ __forceinline__ u16 f2bf(float f) {
    return (u16)((__float_as_uint(f) + 0x8000u) >> 16);
}
__device__ __forceinline__ float bf2f(u16 u) {
    return __uint_as_float(((unsigned)u) << 16);
}
#define MFMA16(a,b,c) __builtin_amdgcn_mfma_f32_16x16x32_bf16((a),(b),(c),0,0,0)

// ---------------------------------------------------------------------------
// prep: obs fp32 -> bf16
// ---------------------------------------------------------------------------
__global__ __launch_bounds__(256) void conv_obs_k(
    const float* __restrict__ obs, u16* __restrict__ obs_bf)
{
    const int i = (blockIdx.x * 256 + threadIdx.x) * 4;
    const float4 v = *(const float4*)(obs + i);
    u16x4 o;
    o[0] = f2bf(v.x); o[1] = f2bf(v.y); o[2] = f2bf(v.z); o[3] = f2bf(v.w);
    *(u16x4*)(obs_bf + i) = o;
}

// ---------------------------------------------------------------------------
// prep: all weights fp32 [in][out] -> bf16 [out][in]
// ---------------------------------------------------------------------------
__global__ __launch_bounds__(256) void prep_w_k(
    const float* __restrict__ W1, const float* __restrict__ W2,
    const float* __restrict__ Wc, const float* __restrict__ Wd,
    const float* __restrict__ Wb, const float* __restrict__ Wr1,
    const float* __restrict__ Wr2,
    u16* __restrict__ Wt1, u16* __restrict__ Wt2, u16* __restrict__ Wtc,
    u16* __restrict__ Wtd, u16* __restrict__ WtB, u16* __restrict__ Wtr1,
    u16* __restrict__ Wtr2)
{
    const int t = blockIdx.x * 256 + threadIdx.x;
    const float* src; u16* dst; int I, os, loc;
    if      (t <  32768) { src = W1;  dst = Wt1;  I = 256; os = 7; loc = t; }
    else if (t <  40960) { src = W2;  dst = Wt2;  I = 128; os = 6; loc = t - 32768; }
    else if (t <  43008) { src = Wc;  dst = Wtc;  I = 64;  os = 5; loc = t - 40960; }
    else if (t <  45056) { src = Wd;  dst = Wtd;  I = 32;  os = 6; loc = t - 43008; }
    else if (t < 110592) { src = Wb;  dst = WtB;  I = 256; os = 8; loc = t - 45056; }
    else if (t < 192512) { src = Wr1; dst = Wtr1; I = 320; os = 8; loc = t - 110592; }
    else                 { src = Wr2; dst = Wtr2; I = 256; os = 8; loc = t - 192512; }
    const int i = loc >> os;
    const int o = loc & ((1 << os) - 1);
    dst[(size_t)o * I + i] = f2bf(src[loc]);
}

// ---------------------------------------------------------------------------
// send v3: 16 rows/block, 2 waves, n-split per layer (waves own disjoint
// output columns; barrier between layers). 2048 blocks -> 16 waves/CU.
// ---------------------------------------------------------------------------
__global__ __launch_bounds__(128) void send_k3(
    const u16* __restrict__ obs_bf,
    const u16* __restrict__ Wt1, const float* __restrict__ b1,
    const u16* __restrict__ Wt2, const float* __restrict__ b2,
    const u16* __restrict__ Wtc, const float* __restrict__ bc,
    const u16* __restrict__ Wtd, const float* __restrict__ bd,
    u16* __restrict__ msgs_bf)
{
    __shared__ u16 sH[16][136];
    __shared__ u16 sF[16][72];
    __shared__ u16 sC[16][40];
    const int t = threadIdx.x;
    const int w = t >> 6, l = t & 63, q = l >> 4, ls = l & 15;
    const int row0 = blockIdx.x * 16;

    // L1: 256 -> 128, relu; wave w owns n = w*4 .. w*4+3
    {
        f32x4 acc[4];
        #pragma unroll
        for (int n = 0; n < 4; ++n) acc[n] = (f32x4){0,0,0,0};
        #pragma unroll
        for (int kk = 0; kk < 8; ++kk) {
            const int k0 = kk * 32;
            const short8 a = *(const short8*)(obs_bf + (size_t)(row0 + ls)*256 + k0 + q*8);
            #pragma unroll
            for (int nn = 0; nn < 4; ++nn) {
                const int n = w*4 + nn;
                const short8 bfr = *(const short8*)(Wt1 + (size_t)(n*16 + ls)*256 + k0 + q*8);
                acc[nn] = MFMA16(a, bfr, acc[nn]);
            }
        }
        #pragma unroll
        for (int nn = 0; nn < 4; ++nn) {
            const int n = w*4 + nn;
            const float bv = b1[n*16 + ls];
            #pragma unroll
            for (int r = 0; r < 4; ++r)
                sH[q*4 + r][n*16 + ls] = f2bf(fmaxf(acc[nn][r] + bv, 0.0f));
        }
    }
    __syncthreads();
    // L2: 128 -> 64; wave w owns n = w*2, w*2+1
    {
        f32x4 acc[2];
        acc[0] = (f32x4){0,0,0,0}; acc[1] = (f32x4){0,0,0,0};
        #pragma unroll
        for (int kk = 0; kk < 4; ++kk) {
            const int k0 = kk * 32;
            const short8 a = *(const short8*)(&sH[ls][k0 + q*8]);
            #pragma unroll
            for (int nn = 0; nn < 2; ++nn) {
                const int n = w*2 + nn;
                const short8 bfr = *(const short8*)(Wt2 + (size_t)(n*16 + ls)*128 + k0 + q*8);
                acc[nn] = MFMA16(a, bfr, acc[nn]);
            }
        }
        #pragma unroll
        for (int nn = 0; nn < 2; ++nn) {
            const int n = w*2 + nn;
            const float bv = b2[n*16 + ls];
            #pragma unroll
            for (int r = 0; r < 4; ++r)
                sF[q*4 + r][n*16 + ls] = f2bf(acc[nn][r] + bv);
        }
    }
    __syncthreads();
    // L3: 64 -> 32; wave w owns n = w
    {
        f32x4 acc = (f32x4){0,0,0,0};
        #pragma unroll
        for (int kk = 0; kk < 2; ++kk) {
            const int k0 = kk * 32;
            const short8 a = *(const short8*)(&sF[ls][k0 + q*8]);
            const short8 bfr = *(const short8*)(Wtc + (size_t)(w*16 + ls)*64 + k0 + q*8);
            acc = MFMA16(a, bfr, acc);
        }
        const float bv = bc[w*16 + ls];
        #pragma unroll
        for (int r = 0; r < 4; ++r)
            sC[q*4 + r][w*16 + ls] = f2bf(acc[r] + bv);
    }
    __syncthreads();
    // L4: 32 -> 64; wave w owns n = w*2, w*2+1; write msgs
    {
        f32x4 acc[2];
        acc[0] = (f32x4){0,0,0,0}; acc[1] = (f32x4){0,0,0,0};
        const short8 a = *(const short8*)(&sC[ls][q*8]);
        #pragma unroll
        for (int nn = 0; nn < 2; ++nn) {
            const int n = w*2 + nn;
            const short8 bfr = *(const short8*)(Wtd + (size_t)(n*16 + ls)*32 + q*8);
            acc[nn] = MFMA16(a, bfr, acc[nn]);
        }
        #pragma unroll
        for (int nn = 0; nn < 2; ++nn) {
            const int n = w*2 + nn;
            const float bv = bd[n*16 + ls];
            #pragma unroll
            for (int r = 0; r < 4; ++r)
                msgs_bf[(size_t)(row0 + q*4 + r)*MSG + n*16 + ls] = f2bf(acc[nn][r] + bv);
        }
    }
}

// ---------------------------------------------------------------------------
// rel GEMM: tmp = obs_i @ Wbil ; scores = tmp @ obs_b^T + bbil -> global bf16.
// 16 rows/block, 2 waves n-split, XCD-swizzled. 2048 blocks.
// ---------------------------------------------------------------------------
__global__ __launch_bounds__(128) void rel_g_k(
    const u16* __restrict__ obs_bf, const u16* __restrict__ WtB,
    const float* __restrict__ bbil, u16* __restrict__ scores)
{
    __shared__ u16 sT[16][264];
    const int t = threadIdx.x;
    const int w = t >> 6, l = t & 63, q = l >> 4, ls = l & 15;
    const int bid = blockIdx.x;
    // swizzle: all 16 blocks of batch b share bid%8 -> one XCD fetches obs_b
    const int b   = (bid & 7) * 16 + (bid >> 7);
    const int i16 = (bid >> 3) & 15;
    const int row0 = b * NN + i16 * 16;

    // P2: tmp[m][e]; wave w owns e-tiles n = w*8 .. w*8+7
    {
        f32x4 acc[8];
        #pragma unroll
        for (int n = 0; n < 8; ++n) acc[n] = (f32x4){0,0,0,0};
        #pragma unroll
        for (int kk = 0; kk < 8; ++kk) {
            const int k0 = kk * 32;
            const short8 a = *(const short8*)(obs_bf + (size_t)(row0 + ls)*256 + k0 + q*8);
            #pragma unroll
            for (int nn = 0; nn < 8; ++nn) {
                const int n = w*8 + nn;
                const short8 bfr = *(const short8*)(WtB + (size_t)(n*16 + ls)*256 + k0 + q*8);
                acc[nn] = MFMA16(a, bfr, acc[nn]);
            }
        }
        #pragma unroll
        for (int nn = 0; nn < 8; ++nn) {
            const int n = w*8 + nn;
            #pragma unroll
            for (int r = 0; r < 4; ++r)
                sT[q*4 + r][n*16 + ls] = f2bf(acc[nn][r]);
        }
    }
    __syncthreads();
    // P3: scores[m][j]; wave w owns j-tiles n = w*8 .. w*8+7
    {
        const float bb = bbil[0];
        f32x4 acc[8];
        #pragma unroll
        for (int n = 0; n < 8; ++n) acc[n] = (f32x4){0,0,0,0};
        #pragma unroll
        for (int kk = 0; kk < 8; ++kk) {
            const int k0 = kk * 32;
            const short8 a = *(const short8*)(&sT[ls][k0 + q*8]);
            #pragma unroll
            for (int nn = 0; nn < 8; ++nn) {
                const int n = w*8 + nn;
                const short8 bfr = *(const short8*)(obs_bf + (size_t)(b*NN + n*16 + ls)*256 + k0 + q*8);
                acc[nn] = MFMA16(a, bfr, acc[nn]);
            }
        }
        #pragma unroll
        for (int nn = 0; nn < 8; ++nn) {
            const int n = w*8 + nn;
            #pragma unroll
            for (int r = 0; r < 4; ++r)
                scores[(size_t)(row0 + q*4 + r)*NN + n*16 + ls] = f2bf(acc[nn][r] + bb);
        }
    }
}

// ---------------------------------------------------------------------------
// topk: per-row top-8 + softmax gates + gather-aggregate msgs.
// 64 rows/block, 256 threads. Scan: 4 threads/row, 64 elems each (branchless
// sorted insert, strict > keeps lowest index on ties), 2-step shuffle merge.
// Gather: 4 waves x 16 rows, lane = msg column (coalesced 128B loads).
// ---------------------------------------------------------------------------
__global__ __launch_bounds__(256) void topk_k(
    const u16* __restrict__ scores, const u16* __restrict__ msgs_bf,
    u16* __restrict__ agg_bf)
{
    __shared__ u16 sS[64][264];
    __shared__ float sG[64][8];
    __shared__ unsigned short sI[64][8];
    const int t = threadIdx.x;
    const int row0 = blockIdx.x * 64;
    const int b = row0 >> 8;

    // stage 64x256 bf16 scores, coalesced
    #pragma unroll
    for (int it = 0; it < 16; ++it) {
        const int idx = t + 256*it;            // u16x8 unit
        const int r = idx >> 5, c8 = idx & 31;
        *(u16x8*)&sS[r][c8*8] =
            *(const u16x8*)(scores + (size_t)(row0 + r)*NN + c8*8);
    }
    __syncthreads();

    // scan: thread -> row t>>2, sub-lane g = t&3 scans cols 4i+g
    {
        const int r = t >> 2, g = t & 3;
        float val[8]; int idx8[8];
        #pragma unroll
        for (int j = 0; j < 8; ++j) { val[j] = -3.4028235e38f; idx8[j] = 1 << 30; }
        for (int i = 0; i < 64; ++i) {
            const int   id = 4*i + g;
            const float v  = bf2f(sS[r][id]);
            // branchless descending insert; strict > => earlier index wins ties
            #pragma unroll
            for (int j = 7; j >= 1; --j) {
                const bool cj  = v > val[j];
                const bool cjm = v > val[j-1];
                val[j]  = cj ? (cjm ? val[j-1]  : v ) : val[j];
                idx8[j] = cj ? (cjm ? idx8[j-1] : id) : idx8[j];
            }
            const bool c0 = v > val[0];
            val[0]  = c0 ? v  : val[0];
            idx8[0] = c0 ? id : idx8[0];
        }
        // merge 4 sorted lists via repeated max-extract (shuffle over 4-group)
        float wv[8]; int wi[8];
        #pragma unroll
        for (int k = 0; k < 8; ++k) {
            float hv = val[0]; int hi = idx8[0];
            float ov; int oi;
            ov = __shfl_xor(hv, 1); oi = __shfl_xor(hi, 1);
            if (ov > hv || (ov == hv && oi < hi)) { hv = ov; hi = oi; }
            ov = __shfl_xor(hv, 2); oi = __shfl_xor(hi, 2);
            if (ov > hv || (ov == hv && oi < hi)) { hv = ov; hi = oi; }
            wv[k] = hv; wi[k] = hi;
            const bool won = (val[0] == hv) && (idx8[0] == hi);
            #pragma unroll
            for (int j = 0; j < 7; ++j) {
                val[j]  = won ? val[j+1]  : val[j];
                idx8[j] = won ? idx8[j+1] : idx8[j];
            }
            val[7]  = won ? -3.4028235e38f : val[7];
            idx8[7] = won ? (1 << 30)      : idx8[7];
        }
        if (g == 0) {
            float e[8]; float s = 0.0f;
            #pragma unroll
            for (int k = 0; k < 8; ++k) { e[k] = __expf(wv[k] - wv[0]); s += e[k]; }
            const float inv = 1.0f / s;
            #pragma unroll
            for (int k = 0; k < 8; ++k) {
                sG[r][k] = e[k] * inv;
                sI[r][k] = (unsigned short)wi[k];
            }
        }
    }
    __syncthreads();

    // gather-aggregate: wave w4 handles rows w4*16..+15; lane = msg column
    {
        const int w4 = t >> 6, l = t & 63;
        for (int rr = 0; rr < 16; ++rr) {
            const int row = w4*16 + rr;
            float a = 0.0f;
            #pragma unroll
            for (int k = 0; k < 8; ++k) {
                const float gt = sG[row][k];
                const int   id = sI[row][k];
                a = fmaf(gt, bf2f(msgs_bf[((size_t)b*NN + id)*MSG + l]), a);
            }
            agg_bf[(size_t)(row0 + row)*MSG + l] = f2bf(a);
        }
    }
}

// ---------------------------------------------------------------------------
// recv v3: 16 rows/block, 2 waves n-split. [obs|agg](320) -> relu(256) -> 256.
// ---------------------------------------------------------------------------
__global__ __launch_bounds__(128) void recv_k3(
    const u16* __restrict__ obs_bf, const u16* __restrict__ agg_bf,
    const u16* __restrict__ Wtr1, const float* __restrict__ br1,
    const u16* __restrict__ Wtr2, const float* __restrict__ br2,
    float* __restrict__ out)
{
    __shared__ u16 sR[16][264];
    const int t = threadIdx.x;
    const int w = t >> 6, l = t & 63, q = l >> 4, ls = l & 15;
    const int row0 = blockIdx.x * 16;

    // L1: K=320 -> 256, relu; wave w owns n = w*8 .. w*8+7
    {
        f32x4 acc[8];
        #pragma unroll
        for (int n = 0; n < 8; ++n) acc[n] = (f32x4){0,0,0,0};
        #pragma unroll
        for (int kk = 0; kk < 10; ++kk) {
            const int k0 = kk * 32;
            const u16* ap = (k0 < 256)
                ? obs_bf + (size_t)(row0 + ls)*256 + k0 + q*8
                : agg_bf + (size_t)(row0 + ls)*64  + (k0 - 256) + q*8;
            const short8 a = *(const short8*)ap;
            #pragma unroll
            for (int nn = 0; nn < 8; ++nn) {
                const int n = w*8 + nn;
                const short8 bfr = *(const short8*)(Wtr1 + (size_t)(n*16 + ls)*320 + k0 + q*8);
                acc[nn] = MFMA16(a, bfr, acc[nn]);
            }
        }
        #pragma unroll
        for (int nn = 0; nn < 8; ++nn) {
            const int n = w*8 + nn;
            const float bv = br1[n*16 + ls];
            #pragma unroll
            for (int r = 0; r < 4; ++r)
                sR[q*4 + r][n*16 + ls] = f2bf(fmaxf(acc[nn][r] + bv, 0.0f));
        }
    }
    __syncthreads();
    // L2: 256 -> 256, fp32 out; wave w owns n = w*8 .. w*8+7
    {
        f32x4 acc[8];
        #pragma unroll
        for (int n = 0; n < 8; ++n) acc[n] = (f32x4){0,0,0,0};
        #pragma unroll
        for (int kk = 0; kk < 8; ++kk) {
            const int k0 = kk * 32;
            const short8 a = *(const short8*)(&sR[ls][k0 + q*8]);
            #pragma unroll
            for (int nn = 0; nn < 8; ++nn) {
                const int n = w*8 + nn;
                const short8 bfr = *(const short8*)(Wtr2 + (size_t)(n*16 + ls)*256 + k0 + q*8);
                acc[nn] = MFMA16(a, bfr, acc[nn]);
            }
        }
        #pragma unroll
        for (int nn = 0; nn < 8; ++nn) {
            const int n = w*8 + nn;
            const float bv = br2[n*16 + ls];
            #pragma unroll
            for (int r = 0; r < 4; ++r)
                out[(size_t)(row0 + q*4 + r)*DIMD + n*16 + ls] = acc[nn][r] + bv;
        }
    }
}

// ---------------------------------------------------------------------------
extern "C" void kernel_launch(void* const* d_in, const int* in_sizes, int n_in,
                              void* d_out, int out_size, void* d_ws, size_t ws_size,
                              hipStream_t stream)
{
    (void)in_sizes; (void)n_in; (void)out_size; (void)ws_size;
    const float* obs  = (const float*)d_in[0];
    const float* W1   = (const float*)d_in[1];
    const float* b1   = (const float*)d_in[2];
    const float* W2   = (const float*)d_in[3];
    const float* b2   = (const float*)d_in[4];
    const float* Wc   = (const float*)d_in[5];
    const float* bc   = (const float*)d_in[6];
    const float* Wd   = (const float*)d_in[7];
    const float* bd   = (const float*)d_in[8];
    const float* Wbil = (const float*)d_in[9];
    const float* bbil = (const float*)d_in[10];
    const float* Wr1  = (const float*)d_in[11];
    const float* br1  = (const float*)d_in[12];
    const float* Wr2  = (const float*)d_in[13];
    const float* br2  = (const float*)d_in[14];
    float* outp = (float*)d_out;

    // workspace (u16 elements): ~42.5 MB total (ws >= 48 MB proven in R2)
    u16* obs_bf  = (u16*)d_ws;                    // BN*256
    u16* msgs_bf = obs_bf  + (size_t)BN*256;      // BN*64
    u16* agg_bf  = msgs_bf + (size_t)BN*64;       // BN*64
    u16* scores  = agg_bf  + (size_t)BN*64;       // BN*256
    u16* Wt1  = scores + (size_t)BN*256;          // 32768
    u16* Wt2  = Wt1  + 32768;
    u16* Wtc  = Wt2  + 8192;
    u16* Wtd  = Wtc  + 2048;
    u16* WtB  = Wtd  + 2048;
    u16* Wtr1 = WtB  + 65536;
    u16* Wtr2 = Wtr1 + 81920;

    conv_obs_k<<<(size_t)BN*256/1024, 256, 0, stream>>>(obs, obs_bf);
    prep_w_k<<<1008, 256, 0, stream>>>(W1, W2, Wc, Wd, Wbil, Wr1, Wr2,
                                       Wt1, Wt2, Wtc, Wtd, WtB, Wtr1, Wtr2);
    send_k3<<<BN/16, 128, 0, stream>>>(obs_bf, Wt1, b1, Wt2, b2, Wtc, bc, Wtd, bd, msgs_bf);
    rel_g_k<<<BN/16, 128, 0, stream>>>(obs_bf, WtB, bbil, scores);
    topk_k <<<BN/64, 256, 0, stream>>>(scores, msgs_bf, agg_bf);
    recv_k3<<<BN/16, 128, 0, stream>>>(obs_bf, agg_bf, Wtr1, br1, Wtr2, br2, outp);
}

// Round 6
// 258.323 us; speedup vs baseline: 2.7374x; 1.1212x over previous
//
#include <hip/hip_runtime.h>
#include <cstddef>

// Problem constants
#define BB   128
#define NN   256
#define DIMD 256
#define MSG  64
#define CDIM 32
#define TOPK 8
#define H1D  128
#define H2D  256
#define BN   (BB*NN)   // 32768 rows

typedef unsigned short u16;
typedef u16   u16x4  __attribute__((ext_vector_type(4)));
typedef u16   u16x8  __attribute__((ext_vector_type(8)));
typedef short short8 __attribute__((ext_vector_type(8)));
typedef float f32x4  __attribute__((ext_vector_type(4)));

__device__ __forceinline__ u16 f2bf(float f) {
    return (u16)((__float_as_uint(f) + 0x8000u) >> 16);
}
__device__ __forceinline__ float bf2f(u16 u) {
    return __uint_as_float(((unsigned)u) << 16);
}
#define MFMA16(a,b,c) __builtin_amdgcn_mfma_f32_16x16x32_bf16((a),(b),(c),0,0,0)

// ---------------------------------------------------------------------------
// prep: obs fp32 -> bf16
// ---------------------------------------------------------------------------
__global__ __launch_bounds__(256) void conv_obs_k(
    const float* __restrict__ obs, u16* __restrict__ obs_bf)
{
    const int i = (blockIdx.x * 256 + threadIdx.x) * 4;
    const float4 v = *(const float4*)(obs + i);
    u16x4 o;
    o[0] = f2bf(v.x); o[1] = f2bf(v.y); o[2] = f2bf(v.z); o[3] = f2bf(v.w);
    *(u16x4*)(obs_bf + i) = o;
}

// ---------------------------------------------------------------------------
// prep: all weights fp32 [in][out] -> bf16 [out][in]
// ---------------------------------------------------------------------------
__global__ __launch_bounds__(256) void prep_w_k(
    const float* __restrict__ W1, const float* __restrict__ W2,
    const float* __restrict__ Wc, const float* __restrict__ Wd,
    const float* __restrict__ Wb, const float* __restrict__ Wr1,
    const float* __restrict__ Wr2,
    u16* __restrict__ Wt1, u16* __restrict__ Wt2, u16* __restrict__ Wtc,
    u16* __restrict__ Wtd, u16* __restrict__ WtB, u16* __restrict__ Wtr1,
    u16* __restrict__ Wtr2)
{
    const int t = blockIdx.x * 256 + threadIdx.x;
    const float* src; u16* dst; int I, os, loc;
    if      (t <  32768) { src = W1;  dst = Wt1;  I = 256; os = 7; loc = t; }
    else if (t <  40960) { src = W2;  dst = Wt2;  I = 128; os = 6; loc = t - 32768; }
    else if (t <  43008) { src = Wc;  dst = Wtc;  I = 64;  os = 5; loc = t - 40960; }
    else if (t <  45056) { src = Wd;  dst = Wtd;  I = 32;  os = 6; loc = t - 43008; }
    else if (t < 110592) { src = Wb;  dst = WtB;  I = 256; os = 8; loc = t - 45056; }
    else if (t < 192512) { src = Wr1; dst = Wtr1; I = 320; os = 8; loc = t - 110592; }
    else                 { src = Wr2; dst = Wtr2; I = 256; os = 8; loc = t - 192512; }
    const int i = loc >> os;
    const int o = loc & ((1 << os) - 1);
    dst[(size_t)o * I + i] = f2bf(src[loc]);
}

// ---------------------------------------------------------------------------
// send v4: 32 rows/block, 4 waves. Each wave: 2 m-tiles, n-split 4 across
// waves. Batched fragment loads (2A+nB per kk) -> compiler can pipeline.
// 1024 blocks x 4 waves = 16 waves/CU.
// ---------------------------------------------------------------------------
__global__ __launch_bounds__(256, 4) void send_k4(
    const u16* __restrict__ obs_bf,
    const u16* __restrict__ Wt1, const float* __restrict__ b1,
    const u16* __restrict__ Wt2, const float* __restrict__ b2,
    const u16* __restrict__ Wtc, const float* __restrict__ bc,
    const u16* __restrict__ Wtd, const float* __restrict__ bd,
    u16* __restrict__ msgs_bf)
{
    __shared__ u16 sH[32][136];
    __shared__ u16 sF[32][72];
    __shared__ u16 sC[32][40];
    const int t = threadIdx.x;
    const int w = t >> 6, l = t & 63, q = l >> 4, ls = l & 15;
    const int row0 = blockIdx.x * 32;

    // L1: 256 -> 128, relu; wave owns n-tiles {2w, 2w+1}
    {
        f32x4 acc[2][2];
        #pragma unroll
        for (int mi = 0; mi < 2; ++mi)
            #pragma unroll
            for (int nn = 0; nn < 2; ++nn) acc[mi][nn] = (f32x4){0,0,0,0};
        #pragma unroll
        for (int kk = 0; kk < 8; ++kk) {
            const int k0 = kk * 32;
            short8 a[2], bf[2];
            #pragma unroll
            for (int mi = 0; mi < 2; ++mi)
                a[mi] = *(const short8*)(obs_bf + (size_t)(row0 + mi*16 + ls)*256 + k0 + q*8);
            #pragma unroll
            for (int nn = 0; nn < 2; ++nn)
                bf[nn] = *(const short8*)(Wt1 + (size_t)((w*2+nn)*16 + ls)*256 + k0 + q*8);
            #pragma unroll
            for (int mi = 0; mi < 2; ++mi)
                #pragma unroll
                for (int nn = 0; nn < 2; ++nn)
                    acc[mi][nn] = MFMA16(a[mi], bf[nn], acc[mi][nn]);
        }
        #pragma unroll
        for (int nn = 0; nn < 2; ++nn) {
            const float bv = b1[(w*2+nn)*16 + ls];
            #pragma unroll
            for (int mi = 0; mi < 2; ++mi)
                #pragma unroll
                for (int r = 0; r < 4; ++r)
                    sH[mi*16 + q*4 + r][(w*2+nn)*16 + ls] = f2bf(fmaxf(acc[mi][nn][r] + bv, 0.0f));
        }
    }
    __syncthreads();
    // L2: 128 -> 64; wave owns n-tile w
    {
        f32x4 acc[2];
        acc[0] = (f32x4){0,0,0,0}; acc[1] = (f32x4){0,0,0,0};
        #pragma unroll
        for (int kk = 0; kk < 4; ++kk) {
            const int k0 = kk * 32;
            short8 a[2];
            a[0] = *(const short8*)(&sH[ls][k0 + q*8]);
            a[1] = *(const short8*)(&sH[16 + ls][k0 + q*8]);
            const short8 bf = *(const short8*)(Wt2 + (size_t)(w*16 + ls)*128 + k0 + q*8);
            acc[0] = MFMA16(a[0], bf, acc[0]);
            acc[1] = MFMA16(a[1], bf, acc[1]);
        }
        const float bv = b2[w*16 + ls];
        #pragma unroll
        for (int mi = 0; mi < 2; ++mi)
            #pragma unroll
            for (int r = 0; r < 4; ++r)
                sF[mi*16 + q*4 + r][w*16 + ls] = f2bf(acc[mi][r] + bv);
    }
    __syncthreads();
    // L3: 64 -> 32; waves 0,1 own n-tile w; waves 2,3 idle
    if (w < 2) {
        f32x4 acc[2];
        acc[0] = (f32x4){0,0,0,0}; acc[1] = (f32x4){0,0,0,0};
        #pragma unroll
        for (int kk = 0; kk < 2; ++kk) {
            const int k0 = kk * 32;
            short8 a[2];
            a[0] = *(const short8*)(&sF[ls][k0 + q*8]);
            a[1] = *(const short8*)(&sF[16 + ls][k0 + q*8]);
            const short8 bf = *(const short8*)(Wtc + (size_t)(w*16 + ls)*64 + k0 + q*8);
            acc[0] = MFMA16(a[0], bf, acc[0]);
            acc[1] = MFMA16(a[1], bf, acc[1]);
        }
        const float bv = bc[w*16 + ls];
        #pragma unroll
        for (int mi = 0; mi < 2; ++mi)
            #pragma unroll
            for (int r = 0; r < 4; ++r)
                sC[mi*16 + q*4 + r][w*16 + ls] = f2bf(acc[mi][r] + bv);
    }
    __syncthreads();
    // L4: 32 -> 64; wave owns n-tile w; write msgs
    {
        f32x4 acc[2];
        acc[0] = (f32x4){0,0,0,0}; acc[1] = (f32x4){0,0,0,0};
        short8 a[2];
        a[0] = *(const short8*)(&sC[ls][q*8]);
        a[1] = *(const short8*)(&sC[16 + ls][q*8]);
        const short8 bf = *(const short8*)(Wtd + (size_t)(w*16 + ls)*32 + q*8);
        acc[0] = MFMA16(a[0], bf, acc[0]);
        acc[1] = MFMA16(a[1], bf, acc[1]);
        const float bv = bd[w*16 + ls];
        #pragma unroll
        for (int mi = 0; mi < 2; ++mi)
            #pragma unroll
            for (int r = 0; r < 4; ++r)
                msgs_bf[(size_t)(row0 + mi*16 + q*4 + r)*MSG + w*16 + ls] = f2bf(acc[mi][r] + bv);
    }
}

// ---------------------------------------------------------------------------
// rel v4 (fused): 32 rows/block (one batch covered by 8 blocks), 4 waves.
// P2: tmp = obs_i @ Wbil (n-split 4) -> LDS. P3: scores = tmp @ obs_b^T
// (n-split 4) -> regs -> LDS. Then in-block top-8 scan + softmax + gather.
// Scores never touch global. XCD-swizzled: one batch per XCD L2.
// ---------------------------------------------------------------------------
__global__ __launch_bounds__(256, 4) void rel_k4(
    const u16* __restrict__ obs_bf, const u16* __restrict__ WtB,
    const float* __restrict__ bbil, const u16* __restrict__ msgs_bf,
    u16* __restrict__ agg_bf)
{
    __shared__ u16 sS[32][264];     // tmp, then scores
    __shared__ float sG[32][8];
    __shared__ unsigned short sI[32][8];
    const int t = threadIdx.x;
    const int w = t >> 6, l = t & 63, q = l >> 4, ls = l & 15;
    const int bid = blockIdx.x;     // 1024
    const int xcd = bid & 7, idx = bid >> 3;
    const int b   = xcd * 16 + (idx >> 3);   // all 8 blocks of b share one XCD
    const int mc  = idx & 7;
    const int row0g = b * NN + mc * 32;

    // P2: tmp[m][e]; wave owns e-tiles w*4..w*4+3, m-tiles 0,1
    {
        f32x4 acc[2][4];
        #pragma unroll
        for (int mi = 0; mi < 2; ++mi)
            #pragma unroll
            for (int nn = 0; nn < 4; ++nn) acc[mi][nn] = (f32x4){0,0,0,0};
        #pragma unroll
        for (int kk = 0; kk < 8; ++kk) {
            const int k0 = kk * 32;
            short8 a[2], bf[4];
            #pragma unroll
            for (int mi = 0; mi < 2; ++mi)
                a[mi] = *(const short8*)(obs_bf + (size_t)(row0g + mi*16 + ls)*256 + k0 + q*8);
            #pragma unroll
            for (int nn = 0; nn < 4; ++nn)
                bf[nn] = *(const short8*)(WtB + (size_t)((w*4+nn)*16 + ls)*256 + k0 + q*8);
            #pragma unroll
            for (int mi = 0; mi < 2; ++mi)
                #pragma unroll
                for (int nn = 0; nn < 4; ++nn)
                    acc[mi][nn] = MFMA16(a[mi], bf[nn], acc[mi][nn]);
        }
        #pragma unroll
        for (int mi = 0; mi < 2; ++mi)
            #pragma unroll
            for (int nn = 0; nn < 4; ++nn)
                #pragma unroll
                for (int r = 0; r < 4; ++r)
                    sS[mi*16 + q*4 + r][(w*4+nn)*16 + ls] = f2bf(acc[mi][nn][r]);
    }
    __syncthreads();
    // P3: scores[m][j]; wave owns j-tiles w*4..w*4+3
    {
        const float bb = bbil[0];
        f32x4 acc[2][4];
        #pragma unroll
        for (int mi = 0; mi < 2; ++mi)
            #pragma unroll
            for (int nn = 0; nn < 4; ++nn) acc[mi][nn] = (f32x4){0,0,0,0};
        #pragma unroll
        for (int kk = 0; kk < 8; ++kk) {
            const int k0 = kk * 32;
            short8 a[2], bf[4];
            a[0] = *(const short8*)(&sS[ls][k0 + q*8]);
            a[1] = *(const short8*)(&sS[16 + ls][k0 + q*8]);
            #pragma unroll
            for (int nn = 0; nn < 4; ++nn)
                bf[nn] = *(const short8*)(obs_bf + (size_t)(b*NN + (w*4+nn)*16 + ls)*256 + k0 + q*8);
            #pragma unroll
            for (int mi = 0; mi < 2; ++mi)
                #pragma unroll
                for (int nn = 0; nn < 4; ++nn)
                    acc[mi][nn] = MFMA16(a[mi], bf[nn], acc[mi][nn]);
        }
        __syncthreads();   // all tmp reads complete before overwrite
        #pragma unroll
        for (int mi = 0; mi < 2; ++mi)
            #pragma unroll
            for (int nn = 0; nn < 4; ++nn)
                #pragma unroll
                for (int r = 0; r < 4; ++r)
                    sS[mi*16 + q*4 + r][(w*4+nn)*16 + ls] = f2bf(acc[mi][nn][r] + bb);
    }
    __syncthreads();
    // scan: 8 threads/row; thread g scans contiguous cols [g*32, g*32+32)
    {
        const int r = t >> 3, g = t & 7;
        u16 buf[32];
        #pragma unroll
        for (int c = 0; c < 4; ++c)
            *(u16x8*)&buf[c*8] = *(const u16x8*)&sS[r][g*32 + c*8];
        float val[8]; int idx8[8];
        #pragma unroll
        for (int j = 0; j < 8; ++j) { val[j] = -3.4028235e38f; idx8[j] = 1 << 30; }
        #pragma unroll
        for (int i = 0; i < 32; ++i) {
            const int   id = g*32 + i;
            const float v  = bf2f(buf[i]);
            // branchless descending insert; strict > => earlier index wins ties
            #pragma unroll
            for (int j = 7; j >= 1; --j) {
                const bool cj  = v > val[j];
                const bool cjm = v > val[j-1];
                val[j]  = cj ? (cjm ? val[j-1]  : v ) : val[j];
                idx8[j] = cj ? (cjm ? idx8[j-1] : id) : idx8[j];
            }
            const bool c0 = v > val[0];
            val[0]  = c0 ? v  : val[0];
            idx8[0] = c0 ? id : idx8[0];
        }
        // merge 8 sorted lists: 8x max-extract over the 8-lane group
        float wv[8]; int wi[8];
        #pragma unroll
        for (int k = 0; k < 8; ++k) {
            float hv = val[0]; int hi = idx8[0];
            float ov; int oi;
            ov = __shfl_xor(hv, 1); oi = __shfl_xor(hi, 1);
            if (ov > hv || (ov == hv && oi < hi)) { hv = ov; hi = oi; }
            ov = __shfl_xor(hv, 2); oi = __shfl_xor(hi, 2);
            if (ov > hv || (ov == hv && oi < hi)) { hv = ov; hi = oi; }
            ov = __shfl_xor(hv, 4); oi = __shfl_xor(hi, 4);
            if (ov > hv || (ov == hv && oi < hi)) { hv = ov; hi = oi; }
            wv[k] = hv; wi[k] = hi;
            const bool won = (val[0] == hv) && (idx8[0] == hi);
            #pragma unroll
            for (int j = 0; j < 7; ++j) {
                val[j]  = won ? val[j+1]  : val[j];
                idx8[j] = won ? idx8[j+1] : idx8[j];
            }
            val[7]  = won ? -3.4028235e38f : val[7];
            idx8[7] = won ? (1 << 30)      : idx8[7];
        }
        if (g == 0) {
            float e[8]; float s = 0.0f;
            #pragma unroll
            for (int k = 0; k < 8; ++k) { e[k] = __expf(wv[k] - wv[0]); s += e[k]; }
            const float inv = 1.0f / s;
            #pragma unroll
            for (int k = 0; k < 8; ++k) {
                sG[r][k] = e[k] * inv;
                sI[r][k] = (unsigned short)wi[k];
            }
        }
    }
    __syncthreads();
    // gather-aggregate: wave w handles rows w*8..w*8+7; lane = msg column
    {
        for (int rr = 0; rr < 8; ++rr) {
            const int row = w*8 + rr;
            float a = 0.0f;
            #pragma unroll
            for (int k = 0; k < 8; ++k) {
                const float gt = sG[row][k];
                const int   id = sI[row][k];
                a = fmaf(gt, bf2f(msgs_bf[((size_t)b*NN + id)*MSG + l]), a);
            }
            agg_bf[(size_t)(row0g + row)*MSG + l] = f2bf(a);
        }
    }
}

// ---------------------------------------------------------------------------
// recv v4: 32 rows/block, 4 waves; wave = 2 m-tiles x 4 n-tiles (n-split 4).
// Batched loads per kk (2A+4B -> 8 MFMA). 1024 blocks -> 16 waves/CU.
// ---------------------------------------------------------------------------
__global__ __launch_bounds__(256, 4) void recv_k4(
    const u16* __restrict__ obs_bf, const u16* __restrict__ agg_bf,
    const u16* __restrict__ Wtr1, const float* __restrict__ br1,
    const u16* __restrict__ Wtr2, const float* __restrict__ br2,
    float* __restrict__ out)
{
    __shared__ u16 sR[32][264];
    const int t = threadIdx.x;
    const int w = t >> 6, l = t & 63, q = l >> 4, ls = l & 15;
    const int row0 = blockIdx.x * 32;

    // L1: K=320 -> 256, relu; wave owns n-tiles w*4..w*4+3
    {
        f32x4 acc[2][4];
        #pragma unroll
        for (int mi = 0; mi < 2; ++mi)
            #pragma unroll
            for (int nn = 0; nn < 4; ++nn) acc[mi][nn] = (f32x4){0,0,0,0};
        #pragma unroll
        for (int kk = 0; kk < 10; ++kk) {
            const int k0 = kk * 32;
            short8 a[2], bf[4];
            #pragma unroll
            for (int mi = 0; mi < 2; ++mi) {
                const u16* ap = (k0 < 256)
                    ? obs_bf + (size_t)(row0 + mi*16 + ls)*256 + k0 + q*8
                    : agg_bf + (size_t)(row0 + mi*16 + ls)*64  + (k0 - 256) + q*8;
                a[mi] = *(const short8*)ap;
            }
            #pragma unroll
            for (int nn = 0; nn < 4; ++nn)
                bf[nn] = *(const short8*)(Wtr1 + (size_t)((w*4+nn)*16 + ls)*320 + k0 + q*8);
            #pragma unroll
            for (int mi = 0; mi < 2; ++mi)
                #pragma unroll
                for (int nn = 0; nn < 4; ++nn)
                    acc[mi][nn] = MFMA16(a[mi], bf[nn], acc[mi][nn]);
        }
        #pragma unroll
        for (int nn = 0; nn < 4; ++nn) {
            const float bv = br1[(w*4+nn)*16 + ls];
            #pragma unroll
            for (int mi = 0; mi < 2; ++mi)
                #pragma unroll
                for (int r = 0; r < 4; ++r)
                    sR[mi*16 + q*4 + r][(w*4+nn)*16 + ls] = f2bf(fmaxf(acc[mi][nn][r] + bv, 0.0f));
        }
    }
    __syncthreads();
    // L2: 256 -> 256, fp32 out; wave owns n-tiles w*4..w*4+3
    {
        f32x4 acc[2][4];
        #pragma unroll
        for (int mi = 0; mi < 2; ++mi)
            #pragma unroll
            for (int nn = 0; nn < 4; ++nn) acc[mi][nn] = (f32x4){0,0,0,0};
        #pragma unroll
        for (int kk = 0; kk < 8; ++kk) {
            const int k0 = kk * 32;
            short8 a[2], bf[4];
            a[0] = *(const short8*)(&sR[ls][k0 + q*8]);
            a[1] = *(const short8*)(&sR[16 + ls][k0 + q*8]);
            #pragma unroll
            for (int nn = 0; nn < 4; ++nn)
                bf[nn] = *(const short8*)(Wtr2 + (size_t)((w*4+nn)*16 + ls)*256 + k0 + q*8);
            #pragma unroll
            for (int mi = 0; mi < 2; ++mi)
                #pragma unroll
                for (int nn = 0; nn < 4; ++nn)
                    acc[mi][nn] = MFMA16(a[mi], bf[nn], acc[mi][nn]);
        }
        #pragma unroll
        for (int nn = 0; nn < 4; ++nn) {
            const float bv = br2[(w*4+nn)*16 + ls];
            #pragma unroll
            for (int mi = 0; mi < 2; ++mi)
                #pragma unroll
                for (int r = 0; r < 4; ++r)
                    out[(size_t)(row0 + mi*16 + q*4 + r)*DIMD + (w*4+nn)*16 + ls] = acc[mi][nn][r] + bv;
        }
    }
}

// ---------------------------------------------------------------------------
extern "C" void kernel_launch(void* const* d_in, const int* in_sizes, int n_in,
                              void* d_out, int out_size, void* d_ws, size_t ws_size,
                              hipStream_t stream)
{
    (void)in_sizes; (void)n_in; (void)out_size; (void)ws_size;
    const float* obs  = (const float*)d_in[0];
    const float* W1   = (const float*)d_in[1];
    const float* b1   = (const float*)d_in[2];
    const float* W2   = (const float*)d_in[3];
    const float* b2   = (const float*)d_in[4];
    const float* Wc   = (const float*)d_in[5];
    const float* bc   = (const float*)d_in[6];
    const float* Wd   = (const float*)d_in[7];
    const float* bd   = (const float*)d_in[8];
    const float* Wbil = (const float*)d_in[9];
    const float* bbil = (const float*)d_in[10];
    const float* Wr1  = (const float*)d_in[11];
    const float* br1  = (const float*)d_in[12];
    const float* Wr2  = (const float*)d_in[13];
    const float* br2  = (const float*)d_in[14];
    float* outp = (float*)d_out;

    // workspace (u16 elements): ~25 MB
    u16* obs_bf  = (u16*)d_ws;                    // BN*256
    u16* msgs_bf = obs_bf  + (size_t)BN*256;      // BN*64
    u16* agg_bf  = msgs_bf + (size_t)BN*64;       // BN*64
    u16* Wt1  = agg_bf + (size_t)BN*64;           // 32768
    u16* Wt2  = Wt1  + 32768;
    u16* Wtc  = Wt2  + 8192;
    u16* Wtd  = Wtc  + 2048;
    u16* WtB  = Wtd  + 2048;
    u16* Wtr1 = WtB  + 65536;
    u16* Wtr2 = Wtr1 + 81920;

    conv_obs_k<<<(size_t)BN*256/1024, 256, 0, stream>>>(obs, obs_bf);
    prep_w_k<<<1008, 256, 0, stream>>>(W1, W2, Wc, Wd, Wbil, Wr1, Wr2,
                                       Wt1, Wt2, Wtc, Wtd, WtB, Wtr1, Wtr2);
    send_k4<<<BN/32, 256, 0, stream>>>(obs_bf, Wt1, b1, Wt2, b2, Wtc, bc, Wtd, bd, msgs_bf);
    rel_k4 <<<BN/32, 256, 0, stream>>>(obs_bf, WtB, bbil, msgs_bf, agg_bf);
    recv_k4<<<BN/32, 256, 0, stream>>>(obs_bf, agg_bf, Wtr1, br1, Wtr2, br2, outp);
}

// Round 7
// 212.687 us; speedup vs baseline: 3.3248x; 1.2146x over previous
//
#include <hip/hip_runtime.h>
#include <cstddef>

// Problem constants
#define BB   128
#define NN   256
#define DIMD 256
#define MSG  64
#define CDIM 32
#define TOPK 8
#define H1D  128
#define H2D  256
#define BN   (BB*NN)   // 32768 rows

typedef unsigned short u16;
typedef u16   u16x4  __attribute__((ext_vector_type(4)));
typedef u16   u16x8  __attribute__((ext_vector_type(8)));
typedef short short8 __attribute__((ext_vector_type(8)));
typedef float f32x4  __attribute__((ext_vector_type(4)));

__device__ __forceinline__ u16 f2bf(float f) {
    return (u16)((__float_as_uint(f) + 0x8000u) >> 16);
}
__device__ __forceinline__ float bf2f(u16 u) {
    return __uint_as_float(((unsigned)u) << 16);
}
#define MFMA16(a,b,c) __builtin_amdgcn_mfma_f32_16x16x32_bf16((a),(b),(c),0,0,0)

// Fragment-linear packing: elem (row16tile, ls=row%16, kk=k/32, q=(k%32)/8,
// j=k%8) lives at ((tile*KB + kk)*64 + q*16 + ls)*8 + j.  A wave's fragment
// load for (tile,kk) is then base + (tile*KB+kk)*512 + lane*8 : one coalesced
// 1KB load instead of 16 scattered 64B segments.

// ---------------------------------------------------------------------------
// prep (merged): blocks [0,8192): obs fp32 -> packed bf16.
//                blocks [8192,9200): weights fp32 [in][out] -> packed bf16.
// ---------------------------------------------------------------------------
__global__ __launch_bounds__(256) void prep_k(
    const float* __restrict__ obs, u16* __restrict__ obs_p,
    const float* __restrict__ W1, const float* __restrict__ W2,
    const float* __restrict__ Wc, const float* __restrict__ Wd,
    const float* __restrict__ Wb, const float* __restrict__ Wr1,
    const float* __restrict__ Wr2,
    u16* __restrict__ Wp1, u16* __restrict__ Wp2, u16* __restrict__ Wpc,
    u16* __restrict__ Wpd, u16* __restrict__ WpB, u16* __restrict__ Wpr1,
    u16* __restrict__ Wpr2)
{
    const int bid = blockIdx.x;
    if (bid < 8192) {
        // obs: thread handles 4 consecutive k of one row
        const int e = (bid * 256 + threadIdx.x) * 4;
        const int r = e >> 8, k = e & 255;
        const float4 v = *(const float4*)(obs + e);
        u16x4 o;
        o[0] = f2bf(v.x); o[1] = f2bf(v.y); o[2] = f2bf(v.z); o[3] = f2bf(v.w);
        const int tile = r >> 4, ls = r & 15;
        const int kk = k >> 5, q = (k & 31) >> 3, j = k & 7;  // j in {0,4}
        *(u16x4*)(obs_p + ((size_t)(tile*8 + kk)*64 + q*16 + ls)*8 + j) = o;
    } else {
        const int t = (bid - 8192) * 256 + threadIdx.x;   // 258048 exactly
        const float* src; u16* dst; int I, os, loc;
        if      (t <  32768) { src = W1;  dst = Wp1;  I = 256; os = 7; loc = t; }
        else if (t <  40960) { src = W2;  dst = Wp2;  I = 128; os = 6; loc = t - 32768; }
        else if (t <  43008) { src = Wc;  dst = Wpc;  I = 64;  os = 5; loc = t - 40960; }
        else if (t <  45056) { src = Wd;  dst = Wpd;  I = 32;  os = 6; loc = t - 43008; }
        else if (t < 110592) { src = Wb;  dst = WpB;  I = 256; os = 8; loc = t - 45056; }
        else if (t < 192512) { src = Wr1; dst = Wpr1; I = 320; os = 8; loc = t - 110592; }
        else                 { src = Wr2; dst = Wpr2; I = 256; os = 8; loc = t - 192512; }
        const int i = loc >> os;                 // input-dim index (k)
        const int o = loc & ((1 << os) - 1);     // output-dim index (n)
        const int nt = o >> 4, ls = o & 15;
        const int KB = I >> 5;
        const int kk = i >> 5, q = (i & 31) >> 3, j = i & 7;
        dst[((size_t)(nt*KB + kk)*64 + q*16 + ls)*8 + j] = f2bf(src[loc]);
    }
}

// ---------------------------------------------------------------------------
// send v5: 32 rows/block, 4 waves, n-split; all fragments via packed loads.
// ---------------------------------------------------------------------------
__global__ __launch_bounds__(256, 4) void send_k5(
    const u16* __restrict__ obs_p,
    const u16* __restrict__ Wp1, const float* __restrict__ b1,
    const u16* __restrict__ Wp2, const float* __restrict__ b2,
    const u16* __restrict__ Wpc, const float* __restrict__ bc,
    const u16* __restrict__ Wpd, const float* __restrict__ bd,
    u16* __restrict__ msgs_bf)
{
    __shared__ u16 sH[32][136];
    __shared__ u16 sF[32][72];
    __shared__ u16 sC[32][40];
    const int t = threadIdx.x;
    const int w = t >> 6, l = t & 63, q = l >> 4, ls = l & 15;
    const int row0 = blockIdx.x * 32;
    const int tile0 = blockIdx.x * 2;

    // L1: 256 -> 128, relu; wave owns n-tiles {2w, 2w+1}
    {
        f32x4 acc[2][2];
        #pragma unroll
        for (int mi = 0; mi < 2; ++mi)
            #pragma unroll
            for (int nn = 0; nn < 2; ++nn) acc[mi][nn] = (f32x4){0,0,0,0};
        #pragma unroll
        for (int kk = 0; kk < 8; ++kk) {
            short8 a[2], bf[2];
            #pragma unroll
            for (int mi = 0; mi < 2; ++mi)
                a[mi] = *(const short8*)(obs_p + ((size_t)((tile0+mi)*8 + kk)*64 + l)*8);
            #pragma unroll
            for (int nn = 0; nn < 2; ++nn)
                bf[nn] = *(const short8*)(Wp1 + ((size_t)((w*2+nn)*8 + kk)*64 + l)*8);
            #pragma unroll
            for (int mi = 0; mi < 2; ++mi)
                #pragma unroll
                for (int nn = 0; nn < 2; ++nn)
                    acc[mi][nn] = MFMA16(a[mi], bf[nn], acc[mi][nn]);
        }
        #pragma unroll
        for (int nn = 0; nn < 2; ++nn) {
            const float bv = b1[(w*2+nn)*16 + ls];
            #pragma unroll
            for (int mi = 0; mi < 2; ++mi)
                #pragma unroll
                for (int r = 0; r < 4; ++r)
                    sH[mi*16 + q*4 + r][(w*2+nn)*16 + ls] = f2bf(fmaxf(acc[mi][nn][r] + bv, 0.0f));
        }
    }
    __syncthreads();
    // L2: 128 -> 64; wave owns n-tile w
    {
        f32x4 acc[2];
        acc[0] = (f32x4){0,0,0,0}; acc[1] = (f32x4){0,0,0,0};
        #pragma unroll
        for (int kk = 0; kk < 4; ++kk) {
            const int k0 = kk * 32;
            short8 a[2];
            a[0] = *(const short8*)(&sH[ls][k0 + q*8]);
            a[1] = *(const short8*)(&sH[16 + ls][k0 + q*8]);
            const short8 bf = *(const short8*)(Wp2 + ((size_t)(w*4 + kk)*64 + l)*8);
            acc[0] = MFMA16(a[0], bf, acc[0]);
            acc[1] = MFMA16(a[1], bf, acc[1]);
        }
        const float bv = b2[w*16 + ls];
        #pragma unroll
        for (int mi = 0; mi < 2; ++mi)
            #pragma unroll
            for (int r = 0; r < 4; ++r)
                sF[mi*16 + q*4 + r][w*16 + ls] = f2bf(acc[mi][r] + bv);
    }
    __syncthreads();
    // L3: 64 -> 32; waves 0,1 active
    if (w < 2) {
        f32x4 acc[2];
        acc[0] = (f32x4){0,0,0,0}; acc[1] = (f32x4){0,0,0,0};
        #pragma unroll
        for (int kk = 0; kk < 2; ++kk) {
            const int k0 = kk * 32;
            short8 a[2];
            a[0] = *(const short8*)(&sF[ls][k0 + q*8]);
            a[1] = *(const short8*)(&sF[16 + ls][k0 + q*8]);
            const short8 bf = *(const short8*)(Wpc + ((size_t)(w*2 + kk)*64 + l)*8);
            acc[0] = MFMA16(a[0], bf, acc[0]);
            acc[1] = MFMA16(a[1], bf, acc[1]);
        }
        const float bv = bc[w*16 + ls];
        #pragma unroll
        for (int mi = 0; mi < 2; ++mi)
            #pragma unroll
            for (int r = 0; r < 4; ++r)
                sC[mi*16 + q*4 + r][w*16 + ls] = f2bf(acc[mi][r] + bv);
    }
    __syncthreads();
    // L4: 32 -> 64; wave owns n-tile w; write msgs (row-major)
    {
        f32x4 acc[2];
        acc[0] = (f32x4){0,0,0,0}; acc[1] = (f32x4){0,0,0,0};
        short8 a[2];
        a[0] = *(const short8*)(&sC[ls][q*8]);
        a[1] = *(const short8*)(&sC[16 + ls][q*8]);
        const short8 bf = *(const short8*)(Wpd + ((size_t)w*64 + l)*8);
        acc[0] = MFMA16(a[0], bf, acc[0]);
        acc[1] = MFMA16(a[1], bf, acc[1]);
        const float bv = bd[w*16 + ls];
        #pragma unroll
        for (int mi = 0; mi < 2; ++mi)
            #pragma unroll
            for (int r = 0; r < 4; ++r)
                msgs_bf[(size_t)(row0 + mi*16 + q*4 + r)*MSG + w*16 + ls] = f2bf(acc[mi][r] + bv);
    }
}

// ---------------------------------------------------------------------------
// rel v5 (fused): 32 rows/block, 4 waves, XCD-swizzled. Packed A/B loads.
// P2 tmp -> LDS; P3 scores -> LDS; scan top-8; softmax; gather msgs;
// agg written in packed layout for recv.
// ---------------------------------------------------------------------------
__global__ __launch_bounds__(256, 4) void rel_k5(
    const u16* __restrict__ obs_p, const u16* __restrict__ WpB,
    const float* __restrict__ bbil, const u16* __restrict__ msgs_bf,
    u16* __restrict__ agg_p)
{
    __shared__ u16 sS[32][264];     // tmp, then scores
    __shared__ float sG[32][8];
    __shared__ unsigned short sI[32][8];
    const int t = threadIdx.x;
    const int w = t >> 6, l = t & 63, q = l >> 4, ls = l & 15;
    const int bid = blockIdx.x;     // 1024
    const int xcd = bid & 7, idx = bid >> 3;
    const int b   = xcd * 16 + (idx >> 3);   // all 8 blocks of b share one XCD
    const int mc  = idx & 7;
    const int row0g = b * NN + mc * 32;
    const int mt0   = b * 16 + mc * 2;       // first m-tile (global 16-row tiles)

    // P2: tmp[m][e]; wave owns e-tiles w*4..w*4+3, m-tiles mt0, mt0+1
    {
        f32x4 acc[2][4];
        #pragma unroll
        for (int mi = 0; mi < 2; ++mi)
            #pragma unroll
            for (int nn = 0; nn < 4; ++nn) acc[mi][nn] = (f32x4){0,0,0,0};
        #pragma unroll
        for (int kk = 0; kk < 8; ++kk) {
            short8 a[2], bf[4];
            #pragma unroll
            for (int mi = 0; mi < 2; ++mi)
                a[mi] = *(const short8*)(obs_p + ((size_t)((mt0+mi)*8 + kk)*64 + l)*8);
            #pragma unroll
            for (int nn = 0; nn < 4; ++nn)
                bf[nn] = *(const short8*)(WpB + ((size_t)((w*4+nn)*8 + kk)*64 + l)*8);
            #pragma unroll
            for (int mi = 0; mi < 2; ++mi)
                #pragma unroll
                for (int nn = 0; nn < 4; ++nn)
                    acc[mi][nn] = MFMA16(a[mi], bf[nn], acc[mi][nn]);
        }
        #pragma unroll
        for (int mi = 0; mi < 2; ++mi)
            #pragma unroll
            for (int nn = 0; nn < 4; ++nn)
                #pragma unroll
                for (int r = 0; r < 4; ++r)
                    sS[mi*16 + q*4 + r][(w*4+nn)*16 + ls] = f2bf(acc[mi][nn][r]);
    }
    __syncthreads();
    // P3: scores[m][j]; wave owns j-tiles w*4..w*4+3 (B = packed obs_b rows)
    {
        const float bb = bbil[0];
        f32x4 acc[2][4];
        #pragma unroll
        for (int mi = 0; mi < 2; ++mi)
            #pragma unroll
            for (int nn = 0; nn < 4; ++nn) acc[mi][nn] = (f32x4){0,0,0,0};
        #pragma unroll
        for (int kk = 0; kk < 8; ++kk) {
            const int k0 = kk * 32;
            short8 a[2], bf[4];
            a[0] = *(const short8*)(&sS[ls][k0 + q*8]);
            a[1] = *(const short8*)(&sS[16 + ls][k0 + q*8]);
            #pragma unroll
            for (int nn = 0; nn < 4; ++nn)
                bf[nn] = *(const short8*)(obs_p + ((size_t)((b*16 + w*4+nn)*8 + kk)*64 + l)*8);
            #pragma unroll
            for (int mi = 0; mi < 2; ++mi)
                #pragma unroll
                for (int nn = 0; nn < 4; ++nn)
                    acc[mi][nn] = MFMA16(a[mi], bf[nn], acc[mi][nn]);
        }
        __syncthreads();   // all tmp reads complete before overwrite
        #pragma unroll
        for (int mi = 0; mi < 2; ++mi)
            #pragma unroll
            for (int nn = 0; nn < 4; ++nn)
                #pragma unroll
                for (int r = 0; r < 4; ++r)
                    sS[mi*16 + q*4 + r][(w*4+nn)*16 + ls] = f2bf(acc[mi][nn][r] + bb);
    }
    __syncthreads();
    // scan: 8 threads/row; thread g scans contiguous cols [g*32, g*32+32)
    {
        const int r = t >> 3, g = t & 7;
        u16 buf[32];
        #pragma unroll
        for (int c = 0; c < 4; ++c)
            *(u16x8*)&buf[c*8] = *(const u16x8*)&sS[r][g*32 + c*8];
        float val[8]; int idx8[8];
        #pragma unroll
        for (int j = 0; j < 8; ++j) { val[j] = -3.4028235e38f; idx8[j] = 1 << 30; }
        #pragma unroll
        for (int i = 0; i < 32; ++i) {
            const int   id = g*32 + i;
            const float v  = bf2f(buf[i]);
            #pragma unroll
            for (int j = 7; j >= 1; --j) {
                const bool cj  = v > val[j];
                const bool cjm = v > val[j-1];
                val[j]  = cj ? (cjm ? val[j-1]  : v ) : val[j];
                idx8[j] = cj ? (cjm ? idx8[j-1] : id) : idx8[j];
            }
            const bool c0 = v > val[0];
            val[0]  = c0 ? v  : val[0];
            idx8[0] = c0 ? id : idx8[0];
        }
        float wv[8]; int wi[8];
        #pragma unroll
        for (int k = 0; k < 8; ++k) {
            float hv = val[0]; int hi = idx8[0];
            float ov; int oi;
            ov = __shfl_xor(hv, 1); oi = __shfl_xor(hi, 1);
            if (ov > hv || (ov == hv && oi < hi)) { hv = ov; hi = oi; }
            ov = __shfl_xor(hv, 2); oi = __shfl_xor(hi, 2);
            if (ov > hv || (ov == hv && oi < hi)) { hv = ov; hi = oi; }
            ov = __shfl_xor(hv, 4); oi = __shfl_xor(hi, 4);
            if (ov > hv || (ov == hv && oi < hi)) { hv = ov; hi = oi; }
            wv[k] = hv; wi[k] = hi;
            const bool won = (val[0] == hv) && (idx8[0] == hi);
            #pragma unroll
            for (int j = 0; j < 7; ++j) {
                val[j]  = won ? val[j+1]  : val[j];
                idx8[j] = won ? idx8[j+1] : idx8[j];
            }
            val[7]  = won ? -3.4028235e38f : val[7];
            idx8[7] = won ? (1 << 30)      : idx8[7];
        }
        if (g == 0) {
            float e[8]; float s = 0.0f;
            #pragma unroll
            for (int k = 0; k < 8; ++k) { e[k] = __expf(wv[k] - wv[0]); s += e[k]; }
            const float inv = 1.0f / s;
            #pragma unroll
            for (int k = 0; k < 8; ++k) {
                sG[r][k] = e[k] * inv;
                sI[r][k] = (unsigned short)wi[k];
            }
        }
    }
    __syncthreads();
    // gather-aggregate: wave w handles rows w*8..w*8+7; lane = msg column.
    // agg written PACKED: (tile, kk=l>>5, q2=(l>>3)&3, j=l&7, ls2=row%16)
    {
        const int kk2 = l >> 5, q2 = (l >> 3) & 3, j2 = l & 7;
        for (int rr = 0; rr < 8; ++rr) {
            const int row = w*8 + rr;
            float a = 0.0f;
            #pragma unroll
            for (int k = 0; k < 8; ++k) {
                const float gt = sG[row][k];
                const int   id = sI[row][k];
                a = fmaf(gt, bf2f(msgs_bf[((size_t)b*NN + id)*MSG + l]), a);
            }
            const int gtile = mt0 + (row >> 4), ls2 = row & 15;
            agg_p[((size_t)(gtile*2 + kk2)*64 + q2*16 + ls2)*8 + j2] = f2bf(a);
        }
    }
}

// ---------------------------------------------------------------------------
// recv v5: 32 rows/block, 4 waves; packed A (obs kk<8, agg kk 8,9) and B.
// ---------------------------------------------------------------------------
__global__ __launch_bounds__(256, 4) void recv_k5(
    const u16* __restrict__ obs_p, const u16* __restrict__ agg_p,
    const u16* __restrict__ Wpr1, const float* __restrict__ br1,
    const u16* __restrict__ Wpr2, const float* __restrict__ br2,
    float* __restrict__ out)
{
    __shared__ u16 sR[32][264];
    const int t = threadIdx.x;
    const int w = t >> 6, l = t & 63, q = l >> 4, ls = l & 15;
    const int row0 = blockIdx.x * 32;
    const int tile0 = blockIdx.x * 2;

    // L1: K=320 -> 256, relu; wave owns n-tiles w*4..w*4+3
    {
        f32x4 acc[2][4];
        #pragma unroll
        for (int mi = 0; mi < 2; ++mi)
            #pragma unroll
            for (int nn = 0; nn < 4; ++nn) acc[mi][nn] = (f32x4){0,0,0,0};
        #pragma unroll
        for (int kk = 0; kk < 10; ++kk) {
            short8 a[2], bf[4];
            #pragma unroll
            for (int mi = 0; mi < 2; ++mi) {
                const u16* ap = (kk < 8)
                    ? obs_p + ((size_t)((tile0+mi)*8 + kk)*64 + l)*8
                    : agg_p + ((size_t)((tile0+mi)*2 + (kk-8))*64 + l)*8;
                a[mi] = *(const short8*)ap;
            }
            #pragma unroll
            for (int nn = 0; nn < 4; ++nn)
                bf[nn] = *(const short8*)(Wpr1 + ((size_t)((w*4+nn)*10 + kk)*64 + l)*8);
            #pragma unroll
            for (int mi = 0; mi < 2; ++mi)
                #pragma unroll
                for (int nn = 0; nn < 4; ++nn)
                    acc[mi][nn] = MFMA16(a[mi], bf[nn], acc[mi][nn]);
        }
        #pragma unroll
        for (int nn = 0; nn < 4; ++nn) {
            const float bv = br1[(w*4+nn)*16 + ls];
            #pragma unroll
            for (int mi = 0; mi < 2; ++mi)
                #pragma unroll
                for (int r = 0; r < 4; ++r)
                    sR[mi*16 + q*4 + r][(w*4+nn)*16 + ls] = f2bf(fmaxf(acc[mi][nn][r] + bv, 0.0f));
        }
    }
    __syncthreads();
    // L2: 256 -> 256, fp32 out; wave owns n-tiles w*4..w*4+3
    {
        f32x4 acc[2][4];
        #pragma unroll
        for (int mi = 0; mi < 2; ++mi)
            #pragma unroll
            for (int nn = 0; nn < 4; ++nn) acc[mi][nn] = (f32x4){0,0,0,0};
        #pragma unroll
        for (int kk = 0; kk < 8; ++kk) {
            const int k0 = kk * 32;
            short8 a[2], bf[4];
            a[0] = *(const short8*)(&sR[ls][k0 + q*8]);
            a[1] = *(const short8*)(&sR[16 + ls][k0 + q*8]);
            #pragma unroll
            for (int nn = 0; nn < 4; ++nn)
                bf[nn] = *(const short8*)(Wpr2 + ((size_t)((w*4+nn)*8 + kk)*64 + l)*8);
            #pragma unroll
            for (int mi = 0; mi < 2; ++mi)
                #pragma unroll
                for (int nn = 0; nn < 4; ++nn)
                    acc[mi][nn] = MFMA16(a[mi], bf[nn], acc[mi][nn]);
        }
        #pragma unroll
        for (int nn = 0; nn < 4; ++nn) {
            const float bv = br2[(w*4+nn)*16 + ls];
            #pragma unroll
            for (int mi = 0; mi < 2; ++mi)
                #pragma unroll
                for (int r = 0; r < 4; ++r)
                    out[(size_t)(row0 + mi*16 + q*4 + r)*DIMD + (w*4+nn)*16 + ls] = acc[mi][nn][r] + bv;
        }
    }
}

// ---------------------------------------------------------------------------
extern "C" void kernel_launch(void* const* d_in, const int* in_sizes, int n_in,
                              void* d_out, int out_size, void* d_ws, size_t ws_size,
                              hipStream_t stream)
{
    (void)in_sizes; (void)n_in; (void)out_size; (void)ws_size;
    const float* obs  = (const float*)d_in[0];
    const float* W1   = (const float*)d_in[1];
    const float* b1   = (const float*)d_in[2];
    const float* W2   = (const float*)d_in[3];
    const float* b2   = (const float*)d_in[4];
    const float* Wc   = (const float*)d_in[5];
    const float* bc   = (const float*)d_in[6];
    const float* Wd   = (const float*)d_in[7];
    const float* bd   = (const float*)d_in[8];
    const float* Wbil = (const float*)d_in[9];
    const float* bbil = (const float*)d_in[10];
    const float* Wr1  = (const float*)d_in[11];
    const float* br1  = (const float*)d_in[12];
    const float* Wr2  = (const float*)d_in[13];
    const float* br2  = (const float*)d_in[14];
    float* outp = (float*)d_out;

    // workspace (u16 elements): ~25 MB
    u16* obs_p   = (u16*)d_ws;                    // BN*256 packed
    u16* msgs_bf = obs_p   + (size_t)BN*256;      // BN*64 row-major
    u16* agg_p   = msgs_bf + (size_t)BN*64;       // BN*64 packed
    u16* Wp1  = agg_p + (size_t)BN*64;            // 32768
    u16* Wp2  = Wp1  + 32768;
    u16* Wpc  = Wp2  + 8192;
    u16* Wpd  = Wpc  + 2048;
    u16* WpB  = Wpd  + 2048;
    u16* Wpr1 = WpB  + 65536;
    u16* Wpr2 = Wpr1 + 81920;

    prep_k<<<8192 + 1008, 256, 0, stream>>>(obs, obs_p, W1, W2, Wc, Wd, Wbil,
                                            Wr1, Wr2, Wp1, Wp2, Wpc, Wpd, WpB,
                                            Wpr1, Wpr2);
    send_k5<<<BN/32, 256, 0, stream>>>(obs_p, Wp1, b1, Wp2, b2, Wpc, bc, Wpd, bd, msgs_bf);
    rel_k5 <<<BN/32, 256, 0, stream>>>(obs_p, WpB, bbil, msgs_bf, agg_p);
    recv_k5<<<BN/32, 256, 0, stream>>>(obs_p, agg_p, Wpr1, br1, Wpr2, br2, outp);
}

// Round 8
// 157.239 us; speedup vs baseline: 4.4973x; 1.3526x over previous
//
#include <hip/hip_runtime.h>
#include <cstddef>

// Problem constants
#define BB   128
#define NN   256
#define DIMD 256
#define MSG  64
#define CDIM 32
#define TOPK 8
#define H1D  128
#define H2D  256
#define BN   (BB*NN)   // 32768 rows

typedef unsigned short u16;
typedef u16   u16x4  __attribute__((ext_vector_type(4)));
typedef u16   u16x8  __attribute__((ext_vector_type(8)));
typedef short short8 __attribute__((ext_vector_type(8)));
typedef float f32x4  __attribute__((ext_vector_type(4)));

__device__ __forceinline__ u16 f2bf(float f) {
    return (u16)((__float_as_uint(f) + 0x8000u) >> 16);
}
__device__ __forceinline__ float bf2f(u16 u) {
    return __uint_as_float(((unsigned)u) << 16);
}
#define MFMA16(a,b,c) __builtin_amdgcn_mfma_f32_16x16x32_bf16((a),(b),(c),0,0,0)

// Fragment-linear packing: elem (row16tile, ls=row%16, kk=k/32, q=(k%32)/8,
// j=k%8) lives at ((tile*KB + kk)*64 + q*16 + ls)*8 + j.  A wave's fragment
// load for (tile,kk) is base + (tile*KB+kk)*512 + lane*8: one coalesced 1KB.

// ---------------------------------------------------------------------------
// prep (merged): blocks [0,8192): obs fp32 -> packed bf16.
//                blocks [8192,9200): weights fp32 [in][out] -> packed bf16.
// ---------------------------------------------------------------------------
__global__ __launch_bounds__(256) void prep_k(
    const float* __restrict__ obs, u16* __restrict__ obs_p,
    const float* __restrict__ W1, const float* __restrict__ W2,
    const float* __restrict__ Wc, const float* __restrict__ Wd,
    const float* __restrict__ Wb, const float* __restrict__ Wr1,
    const float* __restrict__ Wr2,
    u16* __restrict__ Wp1, u16* __restrict__ Wp2, u16* __restrict__ Wpc,
    u16* __restrict__ Wpd, u16* __restrict__ WpB, u16* __restrict__ Wpr1,
    u16* __restrict__ Wpr2)
{
    const int bid = blockIdx.x;
    if (bid < 8192) {
        const int e = (bid * 256 + threadIdx.x) * 4;
        const int r = e >> 8, k = e & 255;
        const float4 v = *(const float4*)(obs + e);
        u16x4 o;
        o[0] = f2bf(v.x); o[1] = f2bf(v.y); o[2] = f2bf(v.z); o[3] = f2bf(v.w);
        const int tile = r >> 4, ls = r & 15;
        const int kk = k >> 5, q = (k & 31) >> 3, j = k & 7;
        *(u16x4*)(obs_p + ((size_t)(tile*8 + kk)*64 + q*16 + ls)*8 + j) = o;
    } else {
        const int t = (bid - 8192) * 256 + threadIdx.x;   // 258048 exactly
        const float* src; u16* dst; int I, os, loc;
        if      (t <  32768) { src = W1;  dst = Wp1;  I = 256; os = 7; loc = t; }
        else if (t <  40960) { src = W2;  dst = Wp2;  I = 128; os = 6; loc = t - 32768; }
        else if (t <  43008) { src = Wc;  dst = Wpc;  I = 64;  os = 5; loc = t - 40960; }
        else if (t <  45056) { src = Wd;  dst = Wpd;  I = 32;  os = 6; loc = t - 43008; }
        else if (t < 110592) { src = Wb;  dst = WpB;  I = 256; os = 8; loc = t - 45056; }
        else if (t < 192512) { src = Wr1; dst = Wpr1; I = 320; os = 8; loc = t - 110592; }
        else                 { src = Wr2; dst = Wpr2; I = 256; os = 8; loc = t - 192512; }
        const int i = loc >> os;
        const int o = loc & ((1 << os) - 1);
        const int nt = o >> 4, ls = o & 15;
        const int KB = I >> 5;
        const int kk = i >> 5, q = (i & 31) >> 3, j = i & 7;
        dst[((size_t)(nt*KB + kk)*64 + q*16 + ls)*8 + j] = f2bf(src[loc]);
    }
}

// ---------------------------------------------------------------------------
// send v6: 32 rows/block, 4 waves, n-split; packed loads; L1 loop has
// explicit depth-1 prefetch (double-buffered fragment regs).
// ---------------------------------------------------------------------------
__global__ __launch_bounds__(256, 4) void send_k6(
    const u16* __restrict__ obs_p,
    const u16* __restrict__ Wp1, const float* __restrict__ b1,
    const u16* __restrict__ Wp2, const float* __restrict__ b2,
    const u16* __restrict__ Wpc, const float* __restrict__ bc,
    const u16* __restrict__ Wpd, const float* __restrict__ bd,
    u16* __restrict__ msgs_bf)
{
    __shared__ u16 sH[32][136];
    __shared__ u16 sF[32][72];
    __shared__ u16 sC[32][40];
    const int t = threadIdx.x;
    const int w = t >> 6, l = t & 63, q = l >> 4, ls = l & 15;
    const int row0 = blockIdx.x * 32;
    const int tile0 = blockIdx.x * 2;

    // L1: 256 -> 128, relu; wave owns n-tiles {2w, 2w+1}; prefetched
    {
        f32x4 acc[2][2];
        #pragma unroll
        for (int mi = 0; mi < 2; ++mi)
            #pragma unroll
            for (int nn = 0; nn < 2; ++nn) acc[mi][nn] = (f32x4){0,0,0,0};
        short8 ca[2], cb[2];
        #pragma unroll
        for (int mi = 0; mi < 2; ++mi)
            ca[mi] = *(const short8*)(obs_p + ((size_t)((tile0+mi)*8))*512 + l*8);
        #pragma unroll
        for (int nn = 0; nn < 2; ++nn)
            cb[nn] = *(const short8*)(Wp1 + ((size_t)((w*2+nn)*8))*512 + l*8);
        #pragma unroll
        for (int kk = 0; kk < 8; ++kk) {
            short8 na[2], nb[2];
            if (kk < 7) {
                #pragma unroll
                for (int mi = 0; mi < 2; ++mi)
                    na[mi] = *(const short8*)(obs_p + ((size_t)((tile0+mi)*8 + kk+1))*512 + l*8);
                #pragma unroll
                for (int nn = 0; nn < 2; ++nn)
                    nb[nn] = *(const short8*)(Wp1 + ((size_t)((w*2+nn)*8 + kk+1))*512 + l*8);
            }
            #pragma unroll
            for (int mi = 0; mi < 2; ++mi)
                #pragma unroll
                for (int nn = 0; nn < 2; ++nn)
                    acc[mi][nn] = MFMA16(ca[mi], cb[nn], acc[mi][nn]);
            if (kk < 7) {
                #pragma unroll
                for (int mi = 0; mi < 2; ++mi) ca[mi] = na[mi];
                #pragma unroll
                for (int nn = 0; nn < 2; ++nn) cb[nn] = nb[nn];
            }
        }
        #pragma unroll
        for (int nn = 0; nn < 2; ++nn) {
            const float bv = b1[(w*2+nn)*16 + ls];
            #pragma unroll
            for (int mi = 0; mi < 2; ++mi)
                #pragma unroll
                for (int r = 0; r < 4; ++r)
                    sH[mi*16 + q*4 + r][(w*2+nn)*16 + ls] = f2bf(fmaxf(acc[mi][nn][r] + bv, 0.0f));
        }
    }
    __syncthreads();
    // L2: 128 -> 64; wave owns n-tile w
    {
        f32x4 acc[2];
        acc[0] = (f32x4){0,0,0,0}; acc[1] = (f32x4){0,0,0,0};
        #pragma unroll
        for (int kk = 0; kk < 4; ++kk) {
            const int k0 = kk * 32;
            short8 a[2];
            a[0] = *(const short8*)(&sH[ls][k0 + q*8]);
            a[1] = *(const short8*)(&sH[16 + ls][k0 + q*8]);
            const short8 bf = *(const short8*)(Wp2 + ((size_t)(w*4 + kk)*64 + l)*8);
            acc[0] = MFMA16(a[0], bf, acc[0]);
            acc[1] = MFMA16(a[1], bf, acc[1]);
        }
        const float bv = b2[w*16 + ls];
        #pragma unroll
        for (int mi = 0; mi < 2; ++mi)
            #pragma unroll
            for (int r = 0; r < 4; ++r)
                sF[mi*16 + q*4 + r][w*16 + ls] = f2bf(acc[mi][r] + bv);
    }
    __syncthreads();
    // L3: 64 -> 32; waves 0,1 active
    if (w < 2) {
        f32x4 acc[2];
        acc[0] = (f32x4){0,0,0,0}; acc[1] = (f32x4){0,0,0,0};
        #pragma unroll
        for (int kk = 0; kk < 2; ++kk) {
            const int k0 = kk * 32;
            short8 a[2];
            a[0] = *(const short8*)(&sF[ls][k0 + q*8]);
            a[1] = *(const short8*)(&sF[16 + ls][k0 + q*8]);
            const short8 bf = *(const short8*)(Wpc + ((size_t)(w*2 + kk)*64 + l)*8);
            acc[0] = MFMA16(a[0], bf, acc[0]);
            acc[1] = MFMA16(a[1], bf, acc[1]);
        }
        const float bv = bc[w*16 + ls];
        #pragma unroll
        for (int mi = 0; mi < 2; ++mi)
            #pragma unroll
            for (int r = 0; r < 4; ++r)
                sC[mi*16 + q*4 + r][w*16 + ls] = f2bf(acc[mi][r] + bv);
    }
    __syncthreads();
    // L4: 32 -> 64; wave owns n-tile w; write msgs (row-major)
    {
        f32x4 acc[2];
        acc[0] = (f32x4){0,0,0,0}; acc[1] = (f32x4){0,0,0,0};
        short8 a[2];
        a[0] = *(const short8*)(&sC[ls][q*8]);
        a[1] = *(const short8*)(&sC[16 + ls][q*8]);
        const short8 bf = *(const short8*)(Wpd + ((size_t)w*64 + l)*8);
        acc[0] = MFMA16(a[0], bf, acc[0]);
        acc[1] = MFMA16(a[1], bf, acc[1]);
        const float bv = bd[w*16 + ls];
        #pragma unroll
        for (int mi = 0; mi < 2; ++mi)
            #pragma unroll
            for (int r = 0; r < 4; ++r)
                msgs_bf[(size_t)(row0 + mi*16 + q*4 + r)*MSG + w*16 + ls] = f2bf(acc[mi][r] + bv);
    }
}

// ---------------------------------------------------------------------------
// relrecv (fused): per block 32 rows of one batch (XCD-swizzled).
//  P2 tmp -> LDS; P3 scores -> LDS; top-8 scan; softmax; gather msgs ->
//  agg in LDS (packed); recv L1 (obs+agg -> relu 256, LDS); recv L2 -> out.
//  All global fragment loops depth-1 prefetched.
// ---------------------------------------------------------------------------
__global__ __launch_bounds__(256, 4) void relrecv_k(
    const u16* __restrict__ obs_p, const u16* __restrict__ WpB,
    const float* __restrict__ bbil, const u16* __restrict__ msgs_bf,
    const u16* __restrict__ Wpr1, const float* __restrict__ br1,
    const u16* __restrict__ Wpr2, const float* __restrict__ br2,
    float* __restrict__ out)
{
    __shared__ u16 sS[32][264];        // tmp -> scores -> recv L1 output
    __shared__ u16 sA[2048];           // agg, packed [mi][kk2][lane][8]
    __shared__ float sG[32][8];
    __shared__ unsigned short sI[32][8];
    const int t = threadIdx.x;
    const int w = t >> 6, l = t & 63, q = l >> 4, ls = l & 15;
    const int bid = blockIdx.x;        // 1024
    const int xcd = bid & 7, idx = bid >> 3;
    const int b   = xcd * 16 + (idx >> 3);
    const int mc  = idx & 7;
    const int row0g = b * NN + mc * 32;
    const int mt0   = b * 16 + mc * 2;

    // P2: tmp[m][e]; wave owns e-tiles w*4..w*4+3; prefetched
    {
        f32x4 acc[2][4];
        #pragma unroll
        for (int mi = 0; mi < 2; ++mi)
            #pragma unroll
            for (int nn = 0; nn < 4; ++nn) acc[mi][nn] = (f32x4){0,0,0,0};
        short8 ca[2], cb[4];
        #pragma unroll
        for (int mi = 0; mi < 2; ++mi)
            ca[mi] = *(const short8*)(obs_p + ((size_t)((mt0+mi)*8))*512 + l*8);
        #pragma unroll
        for (int nn = 0; nn < 4; ++nn)
            cb[nn] = *(const short8*)(WpB + ((size_t)((w*4+nn)*8))*512 + l*8);
        #pragma unroll
        for (int kk = 0; kk < 8; ++kk) {
            short8 na[2], nb[4];
            if (kk < 7) {
                #pragma unroll
                for (int mi = 0; mi < 2; ++mi)
                    na[mi] = *(const short8*)(obs_p + ((size_t)((mt0+mi)*8 + kk+1))*512 + l*8);
                #pragma unroll
                for (int nn = 0; nn < 4; ++nn)
                    nb[nn] = *(const short8*)(WpB + ((size_t)((w*4+nn)*8 + kk+1))*512 + l*8);
            }
            #pragma unroll
            for (int mi = 0; mi < 2; ++mi)
                #pragma unroll
                for (int nn = 0; nn < 4; ++nn)
                    acc[mi][nn] = MFMA16(ca[mi], cb[nn], acc[mi][nn]);
            if (kk < 7) {
                #pragma unroll
                for (int mi = 0; mi < 2; ++mi) ca[mi] = na[mi];
                #pragma unroll
                for (int nn = 0; nn < 4; ++nn) cb[nn] = nb[nn];
            }
        }
        #pragma unroll
        for (int mi = 0; mi < 2; ++mi)
            #pragma unroll
            for (int nn = 0; nn < 4; ++nn)
                #pragma unroll
                for (int r = 0; r < 4; ++r)
                    sS[mi*16 + q*4 + r][(w*4+nn)*16 + ls] = f2bf(acc[mi][nn][r]);
    }
    __syncthreads();
    // P3: scores[m][j]; A from LDS, B = packed obs_b rows (prefetched)
    {
        const float bb = bbil[0];
        f32x4 acc[2][4];
        #pragma unroll
        for (int mi = 0; mi < 2; ++mi)
            #pragma unroll
            for (int nn = 0; nn < 4; ++nn) acc[mi][nn] = (f32x4){0,0,0,0};
        short8 cb[4];
        #pragma unroll
        for (int nn = 0; nn < 4; ++nn)
            cb[nn] = *(const short8*)(obs_p + ((size_t)((b*16 + w*4+nn)*8))*512 + l*8);
        #pragma unroll
        for (int kk = 0; kk < 8; ++kk) {
            short8 nb[4];
            if (kk < 7) {
                #pragma unroll
                for (int nn = 0; nn < 4; ++nn)
                    nb[nn] = *(const short8*)(obs_p + ((size_t)((b*16 + w*4+nn)*8 + kk+1))*512 + l*8);
            }
            const int k0 = kk * 32;
            short8 a[2];
            a[0] = *(const short8*)(&sS[ls][k0 + q*8]);
            a[1] = *(const short8*)(&sS[16 + ls][k0 + q*8]);
            #pragma unroll
            for (int mi = 0; mi < 2; ++mi)
                #pragma unroll
                for (int nn = 0; nn < 4; ++nn)
                    acc[mi][nn] = MFMA16(a[mi], cb[nn], acc[mi][nn]);
            if (kk < 7) {
                #pragma unroll
                for (int nn = 0; nn < 4; ++nn) cb[nn] = nb[nn];
            }
        }
        __syncthreads();   // all tmp reads complete before overwrite
        #pragma unroll
        for (int mi = 0; mi < 2; ++mi)
            #pragma unroll
            for (int nn = 0; nn < 4; ++nn)
                #pragma unroll
                for (int r = 0; r < 4; ++r)
                    sS[mi*16 + q*4 + r][(w*4+nn)*16 + ls] = f2bf(acc[mi][nn][r] + bb);
    }
    __syncthreads();
    // scan: 8 threads/row; thread g scans cols [g*32, g*32+32)
    {
        const int r = t >> 3, g = t & 7;
        u16 buf[32];
        #pragma unroll
        for (int c = 0; c < 4; ++c)
            *(u16x8*)&buf[c*8] = *(const u16x8*)&sS[r][g*32 + c*8];
        float val[8]; int idx8[8];
        #pragma unroll
        for (int j = 0; j < 8; ++j) { val[j] = -3.4028235e38f; idx8[j] = 1 << 30; }
        #pragma unroll
        for (int i = 0; i < 32; ++i) {
            const int   id = g*32 + i;
            const float v  = bf2f(buf[i]);
            if (v > val[7]) {   // semantics-preserving early skip (strict >)
                #pragma unroll
                for (int j = 7; j >= 1; --j) {
                    const bool cj  = v > val[j];
                    const bool cjm = v > val[j-1];
                    val[j]  = cj ? (cjm ? val[j-1]  : v ) : val[j];
                    idx8[j] = cj ? (cjm ? idx8[j-1] : id) : idx8[j];
                }
                const bool c0 = v > val[0];
                val[0]  = c0 ? v  : val[0];
                idx8[0] = c0 ? id : idx8[0];
            }
        }
        float wv[8]; int wi[8];
        #pragma unroll
        for (int k = 0; k < 8; ++k) {
            float hv = val[0]; int hi = idx8[0];
            float ov; int oi;
            ov = __shfl_xor(hv, 1); oi = __shfl_xor(hi, 1);
            if (ov > hv || (ov == hv && oi < hi)) { hv = ov; hi = oi; }
            ov = __shfl_xor(hv, 2); oi = __shfl_xor(hi, 2);
            if (ov > hv || (ov == hv && oi < hi)) { hv = ov; hi = oi; }
            ov = __shfl_xor(hv, 4); oi = __shfl_xor(hi, 4);
            if (ov > hv || (ov == hv && oi < hi)) { hv = ov; hi = oi; }
            wv[k] = hv; wi[k] = hi;
            const bool won = (val[0] == hv) && (idx8[0] == hi);
            #pragma unroll
            for (int j = 0; j < 7; ++j) {
                val[j]  = won ? val[j+1]  : val[j];
                idx8[j] = won ? idx8[j+1] : idx8[j];
            }
            val[7]  = won ? -3.4028235e38f : val[7];
            idx8[7] = won ? (1 << 30)      : idx8[7];
        }
        if (g == 0) {
            float e[8]; float s = 0.0f;
            #pragma unroll
            for (int k = 0; k < 8; ++k) { e[k] = __expf(wv[k] - wv[0]); s += e[k]; }
            const float inv = 1.0f / s;
            #pragma unroll
            for (int k = 0; k < 8; ++k) {
                sG[r][k] = e[k] * inv;
                sI[r][k] = (unsigned short)wi[k];
            }
        }
    }
    __syncthreads();
    // gather-aggregate: wave w rows w*8..w*8+7; lane = msg column.
    // agg -> LDS packed: sA[((mi*2+kk2)*64 + q2*16 + ls2)*8 + j2]
    {
        const int kk2 = l >> 5, q2 = (l >> 3) & 3, j2 = l & 7;
        for (int rr = 0; rr < 8; ++rr) {
            const int row = w*8 + rr;
            float a = 0.0f;
            #pragma unroll
            for (int k = 0; k < 8; ++k) {
                const float gt = sG[row][k];
                const int   id = sI[row][k];
                a = fmaf(gt, bf2f(msgs_bf[((size_t)b*NN + id)*MSG + l]), a);
            }
            const int mi = row >> 4, ls2 = row & 15;
            sA[((mi*2 + kk2)*64 + q2*16 + ls2)*8 + j2] = f2bf(a);
        }
    }
    __syncthreads();
    // recv L1: K=320 -> 256, relu; A: obs (global, kk<8) + agg (LDS, kk 8,9);
    // B: Wpr1 packed (prefetched). Result -> sS (scores are dead).
    {
        f32x4 acc[2][4];
        #pragma unroll
        for (int mi = 0; mi < 2; ++mi)
            #pragma unroll
            for (int nn = 0; nn < 4; ++nn) acc[mi][nn] = (f32x4){0,0,0,0};
        short8 ca[2], cb[4];
        #pragma unroll
        for (int mi = 0; mi < 2; ++mi)
            ca[mi] = *(const short8*)(obs_p + ((size_t)((mt0+mi)*8))*512 + l*8);
        #pragma unroll
        for (int nn = 0; nn < 4; ++nn)
            cb[nn] = *(const short8*)(Wpr1 + ((size_t)((w*4+nn)*10))*512 + l*8);
        #pragma unroll
        for (int kk = 0; kk < 10; ++kk) {
            short8 na[2], nb[4];
            if (kk < 9) {
                if (kk < 7) {
                    #pragma unroll
                    for (int mi = 0; mi < 2; ++mi)
                        na[mi] = *(const short8*)(obs_p + ((size_t)((mt0+mi)*8 + kk+1))*512 + l*8);
                } else {
                    #pragma unroll
                    for (int mi = 0; mi < 2; ++mi)
                        na[mi] = *(const short8*)(&sA[((mi*2 + (kk+1-8))*64 + l)*8]);
                }
                #pragma unroll
                for (int nn = 0; nn < 4; ++nn)
                    nb[nn] = *(const short8*)(Wpr1 + ((size_t)((w*4+nn)*10 + kk+1))*512 + l*8);
            }
            #pragma unroll
            for (int mi = 0; mi < 2; ++mi)
                #pragma unroll
                for (int nn = 0; nn < 4; ++nn)
                    acc[mi][nn] = MFMA16(ca[mi], cb[nn], acc[mi][nn]);
            if (kk < 9) {
                #pragma unroll
                for (int mi = 0; mi < 2; ++mi) ca[mi] = na[mi];
                #pragma unroll
                for (int nn = 0; nn < 4; ++nn) cb[nn] = nb[nn];
            }
        }
        __syncthreads();   // sS scores fully consumed (scan done) before reuse
        #pragma unroll
        for (int nn = 0; nn < 4; ++nn) {
            const float bv = br1[(w*4+nn)*16 + ls];
            #pragma unroll
            for (int mi = 0; mi < 2; ++mi)
                #pragma unroll
                for (int r = 0; r < 4; ++r)
                    sS[mi*16 + q*4 + r][(w*4+nn)*16 + ls] = f2bf(fmaxf(acc[mi][nn][r] + bv, 0.0f));
        }
    }
    __syncthreads();
    // recv L2: 256 -> 256, fp32 out; A from LDS, B Wpr2 (prefetched)
    {
        f32x4 acc[2][4];
        #pragma unroll
        for (int mi = 0; mi < 2; ++mi)
            #pragma unroll
            for (int nn = 0; nn < 4; ++nn) acc[mi][nn] = (f32x4){0,0,0,0};
        short8 cb[4];
        #pragma unroll
        for (int nn = 0; nn < 4; ++nn)
            cb[nn] = *(const short8*)(Wpr2 + ((size_t)((w*4+nn)*8))*512 + l*8);
        #pragma unroll
        for (int kk = 0; kk < 8; ++kk) {
            short8 nb[4];
            if (kk < 7) {
                #pragma unroll
                for (int nn = 0; nn < 4; ++nn)
                    nb[nn] = *(const short8*)(Wpr2 + ((size_t)((w*4+nn)*8 + kk+1))*512 + l*8);
            }
            const int k0 = kk * 32;
            short8 a[2];
            a[0] = *(const short8*)(&sS[ls][k0 + q*8]);
            a[1] = *(const short8*)(&sS[16 + ls][k0 + q*8]);
            #pragma unroll
            for (int mi = 0; mi < 2; ++mi)
                #pragma unroll
                for (int nn = 0; nn < 4; ++nn)
                    acc[mi][nn] = MFMA16(a[mi], cb[nn], acc[mi][nn]);
            if (kk < 7) {
                #pragma unroll
                for (int nn = 0; nn < 4; ++nn) cb[nn] = nb[nn];
            }
        }
        #pragma unroll
        for (int nn = 0; nn < 4; ++nn) {
            const float bv = br2[(w*4+nn)*16 + ls];
            #pragma unroll
            for (int mi = 0; mi < 2; ++mi)
                #pragma unroll
                for (int r = 0; r < 4; ++r)
                    out[(size_t)(row0g + mi*16 + q*4 + r)*DIMD + (w*4+nn)*16 + ls] = acc[mi][nn][r] + bv;
        }
    }
}

// ---------------------------------------------------------------------------
extern "C" void kernel_launch(void* const* d_in, const int* in_sizes, int n_in,
                              void* d_out, int out_size, void* d_ws, size_t ws_size,
                              hipStream_t stream)
{
    (void)in_sizes; (void)n_in; (void)out_size; (void)ws_size;
    const float* obs  = (const float*)d_in[0];
    const float* W1   = (const float*)d_in[1];
    const float* b1   = (const float*)d_in[2];
    const float* W2   = (const float*)d_in[3];
    const float* b2   = (const float*)d_in[4];
    const float* Wc   = (const float*)d_in[5];
    const float* bc   = (const float*)d_in[6];
    const float* Wd   = (const float*)d_in[7];
    const float* bd   = (const float*)d_in[8];
    const float* Wbil = (const float*)d_in[9];
    const float* bbil = (const float*)d_in[10];
    const float* Wr1  = (const float*)d_in[11];
    const float* br1  = (const float*)d_in[12];
    const float* Wr2  = (const float*)d_in[13];
    const float* br2  = (const float*)d_in[14];
    float* outp = (float*)d_out;

    // workspace (u16 elements): ~21 MB
    u16* obs_p   = (u16*)d_ws;                    // BN*256 packed
    u16* msgs_bf = obs_p   + (size_t)BN*256;      // BN*64 row-major
    u16* Wp1  = msgs_bf + (size_t)BN*64;          // 32768
    u16* Wp2  = Wp1  + 32768;
    u16* Wpc  = Wp2  + 8192;
    u16* Wpd  = Wpc  + 2048;
    u16* WpB  = Wpd  + 2048;
    u16* Wpr1 = WpB  + 65536;
    u16* Wpr2 = Wpr1 + 81920;

    prep_k<<<8192 + 1008, 256, 0, stream>>>(obs, obs_p, W1, W2, Wc, Wd, Wbil,
                                            Wr1, Wr2, Wp1, Wp2, Wpc, Wpd, WpB,
                                            Wpr1, Wpr2);
    send_k6<<<BN/32, 256, 0, stream>>>(obs_p, Wp1, b1, Wp2, b2, Wpc, bc, Wpd, bd, msgs_bf);
    relrecv_k<<<BN/32, 256, 0, stream>>>(obs_p, WpB, bbil, msgs_bf,
                                         Wpr1, br1, Wpr2, br2, outp);
}

// Round 9
// 148.256 us; speedup vs baseline: 4.7698x; 1.0606x over previous
//
#include <hip/hip_runtime.h>
#include <cstddef>

// Problem constants
#define BB   128
#define NN   256
#define DIMD 256
#define MSG  64
#define CDIM 32
#define TOPK 8
#define H1D  128
#define H2D  256
#define BN   (BB*NN)   // 32768 rows

typedef unsigned short u16;
typedef u16   u16x4  __attribute__((ext_vector_type(4)));
typedef u16   u16x8  __attribute__((ext_vector_type(8)));
typedef short short8 __attribute__((ext_vector_type(8)));
typedef float f32x4  __attribute__((ext_vector_type(4)));

__device__ __forceinline__ u16 f2bf(float f) {
    return (u16)((__float_as_uint(f) + 0x8000u) >> 16);
}
__device__ __forceinline__ float bf2f(u16 u) {
    return __uint_as_float(((unsigned)u) << 16);
}
#define MFMA16(a,b,c) __builtin_amdgcn_mfma_f32_16x16x32_bf16((a),(b),(c),0,0,0)

// Fragment-linear packing (global): elem (tile=row/16, ls=row%16, kk=k/32,
// q=(k%32)/8, j=k%8) at ((tile*KB+kk)*64 + q*16 + ls)*8 + j. A wave's
// fragment load is one coalesced 1KB transaction.

// ---------------------------------------------------------------------------
// prep: weights fp32 [in][out] -> packed bf16. 1008 blocks exactly.
// ---------------------------------------------------------------------------
__global__ __launch_bounds__(256) void prep_w_k(
    const float* __restrict__ W1, const float* __restrict__ W2,
    const float* __restrict__ Wc, const float* __restrict__ Wd,
    const float* __restrict__ Wb, const float* __restrict__ Wr1,
    const float* __restrict__ Wr2,
    u16* __restrict__ Wp1, u16* __restrict__ Wp2, u16* __restrict__ Wpc,
    u16* __restrict__ Wpd, u16* __restrict__ WpB, u16* __restrict__ Wpr1,
    u16* __restrict__ Wpr2)
{
    const int t = blockIdx.x * 256 + threadIdx.x;   // 258048 exactly
    const float* src; u16* dst; int I, os, loc;
    if      (t <  32768) { src = W1;  dst = Wp1;  I = 256; os = 7; loc = t; }
    else if (t <  40960) { src = W2;  dst = Wp2;  I = 128; os = 6; loc = t - 32768; }
    else if (t <  43008) { src = Wc;  dst = Wpc;  I = 64;  os = 5; loc = t - 40960; }
    else if (t <  45056) { src = Wd;  dst = Wpd;  I = 32;  os = 6; loc = t - 43008; }
    else if (t < 110592) { src = Wb;  dst = WpB;  I = 256; os = 8; loc = t - 45056; }
    else if (t < 192512) { src = Wr1; dst = Wpr1; I = 320; os = 8; loc = t - 110592; }
    else                 { src = Wr2; dst = Wpr2; I = 256; os = 8; loc = t - 192512; }
    const int i = loc >> os;
    const int o = loc & ((1 << os) - 1);
    const int nt = o >> 4, ls = o & 15;
    const int KB = I >> 5;
    const int kk = i >> 5, q = (i & 31) >> 3, j = i & 7;
    dst[((size_t)(nt*KB + kk)*64 + q*16 + ls)*8 + j] = f2bf(src[loc]);
}

// ---------------------------------------------------------------------------
// sendpack: 32 rows/block, 4 waves. Stages fp32 obs -> bf16 LDS, emits
// packed obs_p (coalesced), runs the 4-layer send MLP (L1 A from LDS,
// B prefetched), writes msgs. Replaces the old obs-prep pass entirely.
// ---------------------------------------------------------------------------
__global__ __launch_bounds__(256) __attribute__((amdgpu_waves_per_eu(4, 4)))
void sendpack_k(
    const float* __restrict__ obs, u16* __restrict__ obs_p,
    const u16* __restrict__ Wp1, const float* __restrict__ b1,
    const u16* __restrict__ Wp2, const float* __restrict__ b2,
    const u16* __restrict__ Wpc, const float* __restrict__ bc,
    const u16* __restrict__ Wpd, const float* __restrict__ bd,
    u16* __restrict__ msgs_bf)
{
    __shared__ __align__(16) u16 sO[32][264];
    __shared__ __align__(16) u16 sH[32][136];
    __shared__ __align__(16) u16 sF[32][72];
    __shared__ __align__(16) u16 sC[32][40];
    const int t = threadIdx.x;
    const int w = t >> 6, l = t & 63, q = l >> 4, ls = l & 15;
    const int row0 = blockIdx.x * 32;
    const int tile0 = blockIdx.x * 2;

    // stage obs fp32 -> bf16 LDS (coalesced reads, one row per wave-step)
    {
        const float4* src = (const float4*)(obs + (size_t)row0 * 256);
        #pragma unroll
        for (int i = 0; i < 8; ++i) {
            const int idx = t + 256*i;
            const int r = idx >> 6, c4 = idx & 63;
            const float4 v = src[idx];
            u16x4 o;
            o[0] = f2bf(v.x); o[1] = f2bf(v.y); o[2] = f2bf(v.z); o[3] = f2bf(v.w);
            *(u16x4*)&sO[r][c4*4] = o;
        }
    }
    __syncthreads();
    // emit packed obs_p: LDS b128 reads -> coalesced 1KB global stores
    {
        #pragma unroll
        for (int i = 0; i < 4; ++i) {
            const int u = t + 256*i;                 // 1024 u16x8 units
            const int tile = u >> 9, kk = (u >> 6) & 7, lane = u & 63;
            const u16x8 v = *(const u16x8*)&sO[tile*16 + (lane & 15)][kk*32 + (lane >> 4)*8];
            *(u16x8*)(obs_p + (size_t)(tile0 + tile)*4096 + (size_t)(kk*64 + lane)*8) = v;
        }
    }
    // L1: 256 -> 128, relu; wave owns n-tiles {2w,2w+1}; A from LDS, B prefetched
    {
        f32x4 acc[2][2];
        #pragma unroll
        for (int mi = 0; mi < 2; ++mi)
            #pragma unroll
            for (int nn = 0; nn < 2; ++nn) acc[mi][nn] = (f32x4){0,0,0,0};
        short8 cb[2];
        #pragma unroll
        for (int nn = 0; nn < 2; ++nn)
            cb[nn] = *(const short8*)(Wp1 + ((size_t)((w*2+nn)*8))*512 + l*8);
        #pragma unroll
        for (int kk = 0; kk < 8; ++kk) {
            short8 nb[2];
            if (kk < 7) {
                #pragma unroll
                for (int nn = 0; nn < 2; ++nn)
                    nb[nn] = *(const short8*)(Wp1 + ((size_t)((w*2+nn)*8 + kk+1))*512 + l*8);
            }
            short8 a[2];
            a[0] = *(const short8*)&sO[ls][kk*32 + q*8];
            a[1] = *(const short8*)&sO[16 + ls][kk*32 + q*8];
            #pragma unroll
            for (int mi = 0; mi < 2; ++mi)
                #pragma unroll
                for (int nn = 0; nn < 2; ++nn)
                    acc[mi][nn] = MFMA16(a[mi], cb[nn], acc[mi][nn]);
            if (kk < 7) {
                #pragma unroll
                for (int nn = 0; nn < 2; ++nn) cb[nn] = nb[nn];
            }
        }
        #pragma unroll
        for (int nn = 0; nn < 2; ++nn) {
            const float bv = b1[(w*2+nn)*16 + ls];
            #pragma unroll
            for (int mi = 0; mi < 2; ++mi)
                #pragma unroll
                for (int r = 0; r < 4; ++r)
                    sH[mi*16 + q*4 + r][(w*2+nn)*16 + ls] = f2bf(fmaxf(acc[mi][nn][r] + bv, 0.0f));
        }
    }
    __syncthreads();
    // L2: 128 -> 64; wave owns n-tile w
    {
        f32x4 acc[2];
        acc[0] = (f32x4){0,0,0,0}; acc[1] = (f32x4){0,0,0,0};
        #pragma unroll
        for (int kk = 0; kk < 4; ++kk) {
            const int k0 = kk * 32;
            short8 a[2];
            a[0] = *(const short8*)(&sH[ls][k0 + q*8]);
            a[1] = *(const short8*)(&sH[16 + ls][k0 + q*8]);
            const short8 bf = *(const short8*)(Wp2 + ((size_t)(w*4 + kk)*64 + l)*8);
            acc[0] = MFMA16(a[0], bf, acc[0]);
            acc[1] = MFMA16(a[1], bf, acc[1]);
        }
        const float bv = b2[w*16 + ls];
        #pragma unroll
        for (int mi = 0; mi < 2; ++mi)
            #pragma unroll
            for (int r = 0; r < 4; ++r)
                sF[mi*16 + q*4 + r][w*16 + ls] = f2bf(acc[mi][r] + bv);
    }
    __syncthreads();
    // L3: 64 -> 32; waves 0,1 active
    if (w < 2) {
        f32x4 acc[2];
        acc[0] = (f32x4){0,0,0,0}; acc[1] = (f32x4){0,0,0,0};
        #pragma unroll
        for (int kk = 0; kk < 2; ++kk) {
            const int k0 = kk * 32;
            short8 a[2];
            a[0] = *(const short8*)(&sF[ls][k0 + q*8]);
            a[1] = *(const short8*)(&sF[16 + ls][k0 + q*8]);
            const short8 bf = *(const short8*)(Wpc + ((size_t)(w*2 + kk)*64 + l)*8);
            acc[0] = MFMA16(a[0], bf, acc[0]);
            acc[1] = MFMA16(a[1], bf, acc[1]);
        }
        const float bv = bc[w*16 + ls];
        #pragma unroll
        for (int mi = 0; mi < 2; ++mi)
            #pragma unroll
            for (int r = 0; r < 4; ++r)
                sC[mi*16 + q*4 + r][w*16 + ls] = f2bf(acc[mi][r] + bv);
    }
    __syncthreads();
    // L4: 32 -> 64; wave owns n-tile w; write msgs (row-major)
    {
        f32x4 acc[2];
        acc[0] = (f32x4){0,0,0,0}; acc[1] = (f32x4){0,0,0,0};
        short8 a[2];
        a[0] = *(const short8*)(&sC[ls][q*8]);
        a[1] = *(const short8*)(&sC[16 + ls][q*8]);
        const short8 bf = *(const short8*)(Wpd + ((size_t)w*64 + l)*8);
        acc[0] = MFMA16(a[0], bf, acc[0]);
        acc[1] = MFMA16(a[1], bf, acc[1]);
        const float bv = bd[w*16 + ls];
        #pragma unroll
        for (int mi = 0; mi < 2; ++mi)
            #pragma unroll
            for (int r = 0; r < 4; ++r)
                msgs_bf[(size_t)(row0 + mi*16 + q*4 + r)*MSG + w*16 + ls] = f2bf(acc[mi][r] + bv);
    }
}

// ---------------------------------------------------------------------------
// relrecv (fused): 32 rows of one batch per block (XCD-swizzled).
//  P2 tmp -> LDS; P3 scores -> LDS; top-8 scan; softmax; gather msgs ->
//  agg in LDS (ROW-MAJOR: conflict-free writes, b128 fragment reads);
//  recv L1 -> LDS; recv L2 -> out. Depth-1 prefetch; waves_per_eu(4,4).
// ---------------------------------------------------------------------------
__global__ __launch_bounds__(256) __attribute__((amdgpu_waves_per_eu(4, 4)))
void relrecv_k(
    const u16* __restrict__ obs_p, const u16* __restrict__ WpB,
    const float* __restrict__ bbil, const u16* __restrict__ msgs_bf,
    const u16* __restrict__ Wpr1, const float* __restrict__ br1,
    const u16* __restrict__ Wpr2, const float* __restrict__ br2,
    float* __restrict__ out)
{
    __shared__ __align__(16) u16 sS[32][264];   // tmp -> scores -> recvL1 out
    __shared__ __align__(16) u16 sA[32][72];    // agg, row-major [row][k]
    __shared__ float sG[32][8];
    __shared__ unsigned short sI[32][8];
    const int t = threadIdx.x;
    const int w = t >> 6, l = t & 63, q = l >> 4, ls = l & 15;
    const int bid = blockIdx.x;        // 1024
    const int xcd = bid & 7, idx = bid >> 3;
    const int b   = xcd * 16 + (idx >> 3);
    const int mc  = idx & 7;
    const int row0g = b * NN + mc * 32;
    const int mt0   = b * 16 + mc * 2;

    // P2: tmp[m][e]; wave owns e-tiles w*4..w*4+3; prefetched
    {
        f32x4 acc[2][4];
        #pragma unroll
        for (int mi = 0; mi < 2; ++mi)
            #pragma unroll
            for (int nn = 0; nn < 4; ++nn) acc[mi][nn] = (f32x4){0,0,0,0};
        short8 ca[2], cb[4];
        #pragma unroll
        for (int mi = 0; mi < 2; ++mi)
            ca[mi] = *(const short8*)(obs_p + ((size_t)((mt0+mi)*8))*512 + l*8);
        #pragma unroll
        for (int nn = 0; nn < 4; ++nn)
            cb[nn] = *(const short8*)(WpB + ((size_t)((w*4+nn)*8))*512 + l*8);
        #pragma unroll
        for (int kk = 0; kk < 8; ++kk) {
            short8 na[2], nb[4];
            if (kk < 7) {
                #pragma unroll
                for (int mi = 0; mi < 2; ++mi)
                    na[mi] = *(const short8*)(obs_p + ((size_t)((mt0+mi)*8 + kk+1))*512 + l*8);
                #pragma unroll
                for (int nn = 0; nn < 4; ++nn)
                    nb[nn] = *(const short8*)(WpB + ((size_t)((w*4+nn)*8 + kk+1))*512 + l*8);
            }
            #pragma unroll
            for (int mi = 0; mi < 2; ++mi)
                #pragma unroll
                for (int nn = 0; nn < 4; ++nn)
                    acc[mi][nn] = MFMA16(ca[mi], cb[nn], acc[mi][nn]);
            if (kk < 7) {
                #pragma unroll
                for (int mi = 0; mi < 2; ++mi) ca[mi] = na[mi];
                #pragma unroll
                for (int nn = 0; nn < 4; ++nn) cb[nn] = nb[nn];
            }
        }
        #pragma unroll
        for (int mi = 0; mi < 2; ++mi)
            #pragma unroll
            for (int nn = 0; nn < 4; ++nn)
                #pragma unroll
                for (int r = 0; r < 4; ++r)
                    sS[mi*16 + q*4 + r][(w*4+nn)*16 + ls] = f2bf(acc[mi][nn][r]);
    }
    __syncthreads();
    // P3: scores[m][j]; A from LDS, B = packed obs_b rows (prefetched)
    {
        const float bb = bbil[0];
        f32x4 acc[2][4];
        #pragma unroll
        for (int mi = 0; mi < 2; ++mi)
            #pragma unroll
            for (int nn = 0; nn < 4; ++nn) acc[mi][nn] = (f32x4){0,0,0,0};
        short8 cb[4];
        #pragma unroll
        for (int nn = 0; nn < 4; ++nn)
            cb[nn] = *(const short8*)(obs_p + ((size_t)((b*16 + w*4+nn)*8))*512 + l*8);
        #pragma unroll
        for (int kk = 0; kk < 8; ++kk) {
            short8 nb[4];
            if (kk < 7) {
                #pragma unroll
                for (int nn = 0; nn < 4; ++nn)
                    nb[nn] = *(const short8*)(obs_p + ((size_t)((b*16 + w*4+nn)*8 + kk+1))*512 + l*8);
            }
            const int k0 = kk * 32;
            short8 a[2];
            a[0] = *(const short8*)(&sS[ls][k0 + q*8]);
            a[1] = *(const short8*)(&sS[16 + ls][k0 + q*8]);
            #pragma unroll
            for (int mi = 0; mi < 2; ++mi)
                #pragma unroll
                for (int nn = 0; nn < 4; ++nn)
                    acc[mi][nn] = MFMA16(a[mi], cb[nn], acc[mi][nn]);
            if (kk < 7) {
                #pragma unroll
                for (int nn = 0; nn < 4; ++nn) cb[nn] = nb[nn];
            }
        }
        __syncthreads();   // all tmp reads complete before overwrite
        #pragma unroll
        for (int mi = 0; mi < 2; ++mi)
            #pragma unroll
            for (int nn = 0; nn < 4; ++nn)
                #pragma unroll
                for (int r = 0; r < 4; ++r)
                    sS[mi*16 + q*4 + r][(w*4+nn)*16 + ls] = f2bf(acc[mi][nn][r] + bb);
    }
    __syncthreads();
    // scan: 8 threads/row (rows are wave-private: row t>>3 in wave t>>6)
    {
        const int r = t >> 3, g = t & 7;
        u16 buf[32];
        #pragma unroll
        for (int c = 0; c < 4; ++c)
            *(u16x8*)&buf[c*8] = *(const u16x8*)&sS[r][g*32 + c*8];
        float val[8]; int idx8[8];
        #pragma unroll
        for (int j = 0; j < 8; ++j) { val[j] = -3.4028235e38f; idx8[j] = 1 << 30; }
        #pragma unroll
        for (int i = 0; i < 32; ++i) {
            const int   id = g*32 + i;
            const float v  = bf2f(buf[i]);
            if (v > val[7]) {   // semantics-preserving early skip (strict >)
                #pragma unroll
                for (int j = 7; j >= 1; --j) {
                    const bool cj  = v > val[j];
                    const bool cjm = v > val[j-1];
                    val[j]  = cj ? (cjm ? val[j-1]  : v ) : val[j];
                    idx8[j] = cj ? (cjm ? idx8[j-1] : id) : idx8[j];
                }
                const bool c0 = v > val[0];
                val[0]  = c0 ? v  : val[0];
                idx8[0] = c0 ? id : idx8[0];
            }
        }
        float wv[8]; int wi[8];
        #pragma unroll
        for (int k = 0; k < 8; ++k) {
            float hv = val[0]; int hi = idx8[0];
            float ov; int oi;
            ov = __shfl_xor(hv, 1); oi = __shfl_xor(hi, 1);
            if (ov > hv || (ov == hv && oi < hi)) { hv = ov; hi = oi; }
            ov = __shfl_xor(hv, 2); oi = __shfl_xor(hi, 2);
            if (ov > hv || (ov == hv && oi < hi)) { hv = ov; hi = oi; }
            ov = __shfl_xor(hv, 4); oi = __shfl_xor(hi, 4);
            if (ov > hv || (ov == hv && oi < hi)) { hv = ov; hi = oi; }
            wv[k] = hv; wi[k] = hi;
            const bool won = (val[0] == hv) && (idx8[0] == hi);
            #pragma unroll
            for (int j = 0; j < 7; ++j) {
                val[j]  = won ? val[j+1]  : val[j];
                idx8[j] = won ? idx8[j+1] : idx8[j];
            }
            val[7]  = won ? -3.4028235e38f : val[7];
            idx8[7] = won ? (1 << 30)      : idx8[7];
        }
        if (g == 0) {
            float e[8]; float s = 0.0f;
            #pragma unroll
            for (int k = 0; k < 8; ++k) { e[k] = __expf(wv[k] - wv[0]); s += e[k]; }
            const float inv = 1.0f / s;
            #pragma unroll
            for (int k = 0; k < 8; ++k) {
                sG[r][k] = e[k] * inv;
                sI[r][k] = (unsigned short)wi[k];
            }
        }
    }
    // no barrier: sG/sI/gather rows are wave-private (wave w owns rows w*8..+7)
    // gather-aggregate: lane = msg column; agg -> LDS row-major (coalesced)
    {
        for (int rr = 0; rr < 8; ++rr) {
            const int row = w*8 + rr;
            float a = 0.0f;
            #pragma unroll
            for (int k = 0; k < 8; ++k) {
                const float gt = sG[row][k];
                const int   id = sI[row][k];
                a = fmaf(gt, bf2f(msgs_bf[((size_t)b*NN + id)*MSG + l]), a);
            }
            sA[row][l] = f2bf(a);
        }
    }
    __syncthreads();
    // recv L1: K=320 -> 256, relu; A: obs (global, kk<8) + agg (LDS, kk 8,9)
    {
        f32x4 acc[2][4];
        #pragma unroll
        for (int mi = 0; mi < 2; ++mi)
            #pragma unroll
            for (int nn = 0; nn < 4; ++nn) acc[mi][nn] = (f32x4){0,0,0,0};
        short8 ca[2], cb[4];
        #pragma unroll
        for (int mi = 0; mi < 2; ++mi)
            ca[mi] = *(const short8*)(obs_p + ((size_t)((mt0+mi)*8))*512 + l*8);
        #pragma unroll
        for (int nn = 0; nn < 4; ++nn)
            cb[nn] = *(const short8*)(Wpr1 + ((size_t)((w*4+nn)*10))*512 + l*8);
        #pragma unroll
        for (int kk = 0; kk < 10; ++kk) {
            short8 na[2], nb[4];
            if (kk < 9) {
                if (kk < 7) {
                    #pragma unroll
                    for (int mi = 0; mi < 2; ++mi)
                        na[mi] = *(const short8*)(obs_p + ((size_t)((mt0+mi)*8 + kk+1))*512 + l*8);
                } else {
                    #pragma unroll
                    for (int mi = 0; mi < 2; ++mi)
                        na[mi] = *(const short8*)&sA[mi*16 + ls][(kk+1-8)*32 + q*8];
                }
                #pragma unroll
                for (int nn = 0; nn < 4; ++nn)
                    nb[nn] = *(const short8*)(Wpr1 + ((size_t)((w*4+nn)*10 + kk+1))*512 + l*8);
            }
            #pragma unroll
            for (int mi = 0; mi < 2; ++mi)
                #pragma unroll
                for (int nn = 0; nn < 4; ++nn)
                    acc[mi][nn] = MFMA16(ca[mi], cb[nn], acc[mi][nn]);
            if (kk < 9) {
                #pragma unroll
                for (int mi = 0; mi < 2; ++mi) ca[mi] = na[mi];
                #pragma unroll
                for (int nn = 0; nn < 4; ++nn) cb[nn] = nb[nn];
            }
        }
        __syncthreads();   // sS scores fully consumed (scan done) before reuse
        #pragma unroll
        for (int nn = 0; nn < 4; ++nn) {
            const float bv = br1[(w*4+nn)*16 + ls];
            #pragma unroll
            for (int mi = 0; mi < 2; ++mi)
                #pragma unroll
                for (int r = 0; r < 4; ++r)
                    sS[mi*16 + q*4 + r][(w*4+nn)*16 + ls] = f2bf(fmaxf(acc[mi][nn][r] + bv, 0.0f));
        }
    }
    __syncthreads();
    // recv L2: 256 -> 256, fp32 out; A from LDS, B Wpr2 (prefetched)
    {
        f32x4 acc[2][4];
        #pragma unroll
        for (int mi = 0; mi < 2; ++mi)
            #pragma unroll
            for (int nn = 0; nn < 4; ++nn) acc[mi][nn] = (f32x4){0,0,0,0};
        short8 cb[4];
        #pragma unroll
        for (int nn = 0; nn < 4; ++nn)
            cb[nn] = *(const short8*)(Wpr2 + ((size_t)((w*4+nn)*8))*512 + l*8);
        #pragma unroll
        for (int kk = 0; kk < 8; ++kk) {
            short8 nb[4];
            if (kk < 7) {
                #pragma unroll
                for (int nn = 0; nn < 4; ++nn)
                    nb[nn] = *(const short8*)(Wpr2 + ((size_t)((w*4+nn)*8 + kk+1))*512 + l*8);
            }
            const int k0 = kk * 32;
            short8 a[2];
            a[0] = *(const short8*)(&sS[ls][k0 + q*8]);
            a[1] = *(const short8*)(&sS[16 + ls][k0 + q*8]);
            #pragma unroll
            for (int mi = 0; mi < 2; ++mi)
                #pragma unroll
                for (int nn = 0; nn < 4; ++nn)
                    acc[mi][nn] = MFMA16(a[mi], cb[nn], acc[mi][nn]);
            if (kk < 7) {
                #pragma unroll
                for (int nn = 0; nn < 4; ++nn) cb[nn] = nb[nn];
            }
        }
        #pragma unroll
        for (int nn = 0; nn < 4; ++nn) {
            const float bv = br2[(w*4+nn)*16 + ls];
            #pragma unroll
            for (int mi = 0; mi < 2; ++mi)
                #pragma unroll
                for (int r = 0; r < 4; ++r)
                    out[(size_t)(row0g + mi*16 + q*4 + r)*DIMD + (w*4+nn)*16 + ls] = acc[mi][nn][r] + bv;
        }
    }
}

// ---------------------------------------------------------------------------
extern "C" void kernel_launch(void* const* d_in, const int* in_sizes, int n_in,
                              void* d_out, int out_size, void* d_ws, size_t ws_size,
                              hipStream_t stream)
{
    (void)in_sizes; (void)n_in; (void)out_size; (void)ws_size;
    const float* obs  = (const float*)d_in[0];
    const float* W1   = (const float*)d_in[1];
    const float* b1   = (const float*)d_in[2];
    const float* W2   = (const float*)d_in[3];
    const float* b2   = (const float*)d_in[4];
    const float* Wc   = (const float*)d_in[5];
    const float* bc   = (const float*)d_in[6];
    const float* Wd   = (const float*)d_in[7];
    const float* bd   = (const float*)d_in[8];
    const float* Wbil = (const float*)d_in[9];
    const float* bbil = (const float*)d_in[10];
    const float* Wr1  = (const float*)d_in[11];
    const float* br1  = (const float*)d_in[12];
    const float* Wr2  = (const float*)d_in[13];
    const float* br2  = (const float*)d_in[14];
    float* outp = (float*)d_out;

    // workspace (u16 elements): ~21 MB
    u16* obs_p   = (u16*)d_ws;                    // BN*256 packed
    u16* msgs_bf = obs_p   + (size_t)BN*256;      // BN*64 row-major
    u16* Wp1  = msgs_bf + (size_t)BN*64;          // 32768
    u16* Wp2  = Wp1  + 32768;
    u16* Wpc  = Wp2  + 8192;
    u16* Wpd  = Wpc  + 2048;
    u16* WpB  = Wpd  + 2048;
    u16* Wpr1 = WpB  + 65536;
    u16* Wpr2 = Wpr1 + 81920;

    prep_w_k<<<1008, 256, 0, stream>>>(W1, W2, Wc, Wd, Wbil, Wr1, Wr2,
                                       Wp1, Wp2, Wpc, Wpd, WpB, Wpr1, Wpr2);
    sendpack_k<<<BN/32, 256, 0, stream>>>(obs, obs_p, Wp1, b1, Wp2, b2,
                                          Wpc, bc, Wpd, bd, msgs_bf);
    relrecv_k<<<BN/32, 256, 0, stream>>>(obs_p, WpB, bbil, msgs_bf,
                                         Wpr1, br1, Wpr2, br2, outp);
}